// Round 4
// baseline (252.485 us; speedup 1.0000x reference)
//
#include <hip/hip_runtime.h>
#include <stdint.h>

typedef unsigned short u16;
typedef __attribute__((ext_vector_type(8))) short short8;
typedef __attribute__((ext_vector_type(4))) short short4v;
typedef __attribute__((ext_vector_type(4))) float floatx4;
typedef __attribute__((ext_vector_type(16))) float floatx16;
typedef __attribute__((ext_vector_type(2))) unsigned int uint2v;
typedef __attribute__((ext_vector_type(4))) unsigned int uint4v;

#define AS_GLOBAL __attribute__((address_space(1)))
#define AS_LDS    __attribute__((address_space(3)))

// exp2 argument scale folded into Qp: 1/sqrt(1024) * log2(e)
#define QSCALE 0.045084220f

__device__ __forceinline__ float bf2f(u16 u) {
  union { unsigned int i; float f; } x; x.i = ((unsigned int)u) << 16; return x.f;
}
__device__ __forceinline__ u16 f2bf(float f) {          // RNE
  union { float f; unsigned int i; } x; x.f = f;
  unsigned int u = x.i;
  u += 0x7fffu + ((u >> 16) & 1u);
  return (u16)(u >> 16);
}
__device__ __forceinline__ u16 f2bf_fast(float f) {     // round-half-up, 2 ops
  union { float f; unsigned int i; } x; x.f = f;
  return (u16)((x.i + 0x8000u) >> 16);
}

// pack two f32 -> bf16x2 word (v_cvt_pk_bf16_f32: lo -> [15:0], hi -> [31:16])
__device__ __forceinline__ unsigned int cvtpk_bf16(float lo, float hi) {
  unsigned int w;
  __asm__("v_cvt_pk_bf16_f32 %0, %1, %2" : "=v"(w) : "v"(lo), "v"(hi));
  return w;
}

// paired half-swap (gfx950): a' = {a.lo, b.lo}, b' = {a.hi, b.hi}
__device__ __forceinline__ void pl32_swap(unsigned int& a, unsigned int& b) {
#if __has_builtin(__builtin_amdgcn_permlane32_swap)
  uint2v r = __builtin_amdgcn_permlane32_swap(a, b, false, false);
  a = r[0]; b = r[1];
#else
  __asm__("v_permlane32_swap_b32 %0, %1" : "+v"(a), "+v"(b));
#endif
}

// Runtime dtype probe (R4-validated).
__device__ __forceinline__ int probe_is_f32(const void* p) {
  const unsigned int* w = (const unsigned int*)p;
  int cnt = 0;
#pragma unroll
  for (int i = 0; i < 64; ++i) {
    unsigned int lo = w[i] & 0xFFFFu;
    int e = (int)((lo >> 7) & 0xFFu);
    cnt += (e >= 117 && e <= 137) ? 1 : 0;
  }
  return cnt < 32;
}

__device__ __forceinline__ short8 ld8(const void* P, size_t off, int isf32) {
  if (isf32) {
    const float* q = (const float*)P + off;
    float4 x = *(const float4*)q;
    float4 y = *(const float4*)(q + 4);
    short8 r;
    r[0] = (short)f2bf(x.x); r[1] = (short)f2bf(x.y);
    r[2] = (short)f2bf(x.z); r[3] = (short)f2bf(x.w);
    r[4] = (short)f2bf(y.x); r[5] = (short)f2bf(y.y);
    r[6] = (short)f2bf(y.z); r[7] = (short)f2bf(y.w);
    return r;
  }
  return *(const short8*)((const u16*)P + off);
}

__device__ __forceinline__ float ldscalar(const void* P, size_t idx, int isf32) {
  return isf32 ? ((const float*)P)[idx] : bf2f(((const u16*)P)[idx]);
}

// ---------------------------------------------------------------------------
// cvt7: one-shot fp32->bf16 of 3 X tensors + 4 W tensors. grid (1024, 7).
// ---------------------------------------------------------------------------
__global__ __launch_bounds__(256) void cvt7(
    const void* s0, const void* s1, const void* s2, const void* s3,
    const void* s4, const void* s5, const void* s6,
    u16* d0, u16* d1, u16* d2, u16* d3, u16* d4, u16* d5, u16* d6)
{
  const int z = blockIdx.y;
  const void* src; u16* dst; int n;
  switch (z) {
    case 0: src = s0; dst = d0; n = 4194304; break;
    case 1: src = s1; dst = d1; n = 4194304; break;
    case 2: src = s2; dst = d2; n = 4194304; break;
    case 3: src = s3; dst = d3; n = 1048576; break;
    case 4: src = s4; dst = d4; n = 1048576; break;
    case 5: src = s5; dst = d5; n = 1048576; break;
    default: src = s6; dst = d6; n = 1048576; break;
  }
  const int isf32 = probe_is_f32(src);
  for (int i = blockIdx.x * 256 + threadIdx.x; i * 4 < n; i += gridDim.x * 256) {
    if (isf32) {
      float4 x = ((const float4*)src)[i];
      short4v r;
      r[0] = (short)f2bf(x.x); r[1] = (short)f2bf(x.y);
      r[2] = (short)f2bf(x.z); r[3] = (short)f2bf(x.w);
      *(short4v*)(dst + (size_t)i * 4) = r;
    } else {
      *(short4v*)(dst + (size_t)i * 4) = ((const short4v*)src)[i];
    }
  }
}

// ---------------------------------------------------------------------------
// bf16 MFMA GEMM core v3: BK=32 + DOUBLE-BUFFERED LDS with raw-asm barriers.
// Prefetch for tile k+1 is issued BEFORE the barrier and stays in flight
// across it (s_waitcnt vmcnt(4), never 0 inside the loop).
// As/Bs must each be 8192 u16 (two 4096 buffers). 128x128 tile, 4 waves.
// ---------------------------------------------------------------------------
__device__ __forceinline__ void gemm_core_bf16(
    const u16* __restrict__ A, const u16* __restrict__ W,
    u16* As, u16* Bs, floatx4 acc[4][4], int m0, int n0, int K, int tid)
{
  const int lane = tid & 63, wv = tid >> 6;
  const int wm = wv >> 1, wn = wv & 1;
  const int g = lane >> 4, ml = lane & 15;
  const int r0 = tid >> 2, kc = (tid & 3) << 3;
  const u16* Ag0 = A + (size_t)(m0 + r0) * K + kc;
  const u16* Ag1 = A + (size_t)(m0 + r0 + 64) * K + kc;
  const u16* Bg0 = W + (size_t)(n0 + r0) * K + kc;
  const u16* Bg1 = W + (size_t)(n0 + r0 + 64) * K + kc;

#define STAGE_QKV(buf_, kt_) do {                                              \
    u16* a0 = As + (buf_) * 4096 + tid * 8;                                    \
    u16* b0 = Bs + (buf_) * 4096 + tid * 8;                                    \
    __builtin_amdgcn_global_load_lds((const AS_GLOBAL unsigned int*)(Ag0 + (kt_)), \
                                     (AS_LDS unsigned int*)a0, 16, 0, 0);      \
    __builtin_amdgcn_global_load_lds((const AS_GLOBAL unsigned int*)(Ag1 + (kt_)), \
                                     (AS_LDS unsigned int*)(a0 + 2048), 16, 0, 0); \
    __builtin_amdgcn_global_load_lds((const AS_GLOBAL unsigned int*)(Bg0 + (kt_)), \
                                     (AS_LDS unsigned int*)b0, 16, 0, 0);      \
    __builtin_amdgcn_global_load_lds((const AS_GLOBAL unsigned int*)(Bg1 + (kt_)), \
                                     (AS_LDS unsigned int*)(b0 + 2048), 16, 0, 0); \
  } while (0)

  STAGE_QKV(0, 0);
  int buf = 0;
#pragma unroll 2
  for (int kt = 0; kt < K; kt += 32) {
    const int nk = (kt + 32 < K) ? (kt + 32) : 0;   // dummy reload on last iter
    STAGE_QKV(buf ^ 1, nk);
    // wait current tile (4 oldest), keep prefetch (4 newest) in flight
    __asm__ __volatile__("s_waitcnt vmcnt(4)\n\ts_barrier" ::: "memory");
    const u16* Ac = As + buf * 4096;
    const u16* Bc = Bs + buf * 4096;
    short8 af[4], bf[4];
#pragma unroll
    for (int i = 0; i < 4; ++i)
      af[i] = *(const short8*)(Ac + (wm * 64 + i * 16 + ml) * 32 + g * 8);
#pragma unroll
    for (int j = 0; j < 4; ++j)
      bf[j] = *(const short8*)(Bc + (wn * 64 + j * 16 + ml) * 32 + g * 8);
#pragma unroll
    for (int i = 0; i < 4; ++i)
#pragma unroll
      for (int j = 0; j < 4; ++j)
        acc[i][j] = __builtin_amdgcn_mfma_f32_16x16x32_bf16(af[i], bf[j], acc[i][j], 0, 0, 0);
    // all waves done reading buf before it becomes next prefetch target
    __asm__ __volatile__("s_waitcnt lgkmcnt(0)\n\ts_barrier" ::: "memory");
    buf ^= 1;
  }
#undef STAGE_QKV
  // drain dummy prefetch before epilogue / endpgm (LDS-dealloc hazard)
  __asm__ __volatile__("s_waitcnt vmcnt(0)" ::: "memory");
}

// R7-proven fallback core: BK=32, cvt-in-staging. (As/Bs = 4096 u16)
__device__ __forceinline__ void gemm_core_cvt(
    const void* __restrict__ A, const void* __restrict__ W, int aF32, int bF32,
    u16* As, u16* Bs, floatx4 acc[4][4], int m0, int n0, int K, int tid)
{
  const int lane = tid & 63, wv = tid >> 6;
  const int wm = wv >> 1, wn = wv & 1;
  const int g = lane >> 4, ml = lane & 15;
  const int r0 = tid >> 2, kc = (tid & 3) << 3;
  const size_t offA0 = (size_t)(m0 + r0) * K + kc;
  const size_t offA1 = (size_t)(m0 + r0 + 64) * K + kc;
  const size_t offB0 = (size_t)(n0 + r0) * K + kc;
  const size_t offB1 = (size_t)(n0 + r0 + 64) * K + kc;
  u16* Al0 = As + tid * 8;  u16* Al1 = As + (tid + 256) * 8;
  u16* Bl0 = Bs + tid * 8;  u16* Bl1 = Bs + (tid + 256) * 8;
  for (int kt = 0; kt < K; kt += 32) {
    short8 a0 = ld8(A, offA0 + kt, aF32);
    short8 a1 = ld8(A, offA1 + kt, aF32);
    short8 b0 = ld8(W, offB0 + kt, bF32);
    short8 b1 = ld8(W, offB1 + kt, bF32);
    *(short8*)Al0 = a0;  *(short8*)Al1 = a1;
    *(short8*)Bl0 = b0;  *(short8*)Bl1 = b1;
    __syncthreads();
    short8 af[4], bf[4];
#pragma unroll
    for (int i = 0; i < 4; ++i)
      af[i] = *(const short8*)(As + (wm * 64 + i * 16 + ml) * 32 + g * 8);
#pragma unroll
    for (int j = 0; j < 4; ++j)
      bf[j] = *(const short8*)(Bs + (wn * 64 + j * 16 + ml) * 32 + g * 8);
#pragma unroll
    for (int i = 0; i < 4; ++i)
#pragma unroll
      for (int j = 0; j < 4; ++j)
        acc[i][j] = __builtin_amdgcn_mfma_f32_16x16x32_bf16(af[i], bf[j], acc[i][j], 0, 0, 0);
    __syncthreads();
  }
}

// ---------------------------------------------------------------------------
// QKV epilogue: z=0 (Q) scaled by QSCALE into [B,H,S,D]; z=1 (K) [B,H,S,D];
// z=2 (V) TRANSPOSED into [B,H,D,S] (4-wide packed along s).
// ---------------------------------------------------------------------------
__device__ __forceinline__ void qkv_epilogue(
    floatx4 acc[4][4], const void* Bi, int cF32, u16* O, int m0, int n0,
    int tid, int z)
{
  const int lane = tid & 63, wv = tid >> 6;
  const int wm = wv >> 1, wn = wv & 1, g = lane >> 4, ml = lane & 15;
  const float sc = (z == 0) ? QSCALE : 1.0f;
#pragma unroll
  for (int j = 0; j < 4; ++j) {
    int gn = n0 + wn * 64 + j * 16 + ml;
    float bvv = ldscalar(Bi, (size_t)gn, cF32);
    int h = gn >> 6, d = gn & 63;
    if (z == 2) {
#pragma unroll
      for (int i = 0; i < 4; ++i) {
        int gm0 = m0 + wm * 64 + i * 16 + g * 4;
        int b = gm0 >> 11, s0 = gm0 & 2047;
        short4v pk;
#pragma unroll
        for (int r = 0; r < 4; ++r) pk[r] = (short)f2bf_fast(acc[i][j][r] + bvv);
        *(short4v*)(O + ((((size_t)b * 16 + h) * 64 + d) * 2048 + s0)) = pk;
      }
    } else {
#pragma unroll
      for (int i = 0; i < 4; ++i)
#pragma unroll
        for (int r = 0; r < 4; ++r) {
          int gm = m0 + wm * 64 + i * 16 + g * 4 + r;
          int b = gm >> 11, s = gm & 2047;
          O[(((size_t)b * 16 + h) * 2048 + s) * 64 + d] =
              f2bf_fast((acc[i][j][r] + bvv) * sc);
        }
    }
  }
}

// grid (32 m-tiles, 8 n-tiles, 3): linear index ≡ m (mod 8) -> XCD keeps a
// fixed quarter of A's rows hot and reuses each W tile 4x in its own L2.
__global__ __launch_bounds__(256) void qkv_gemm_bf16(
    const u16* __restrict__ Xq, const u16* __restrict__ Xk, const u16* __restrict__ Xv,
    const u16* __restrict__ Wq, const u16* __restrict__ Wk, const u16* __restrict__ Wv,
    const void* __restrict__ Bq, const void* __restrict__ Bk, const void* __restrict__ Bv,
    u16* __restrict__ Oq, u16* __restrict__ Ok, u16* __restrict__ Ov)
{
  __align__(16) __shared__ u16 As[8192];
  __align__(16) __shared__ u16 Bs[8192];
  const int z = blockIdx.z;
  const u16* X = (z == 0) ? Xq : (z == 1) ? Xk : Xv;
  const u16* W = (z == 0) ? Wq : (z == 1) ? Wk : Wv;
  const void* Bi = (z == 0) ? Bq : (z == 1) ? Bk : Bv;
  u16* O = (z == 0) ? Oq : (z == 1) ? Ok : Ov;
  const int tid = threadIdx.x;
  const int m0 = blockIdx.x * 128, n0 = blockIdx.y * 128;
  floatx4 acc[4][4] = {};
  gemm_core_bf16(X, W, As, Bs, acc, m0, n0, 1024, tid);
  const int cF32 = probe_is_f32(Bi);   // after core: no stray vmem in loop
  qkv_epilogue(acc, Bi, cF32, O, m0, n0, tid, z);
}

__global__ __launch_bounds__(256) void qkv_gemm_cvt(
    const void* __restrict__ Xq, const void* __restrict__ Xk, const void* __restrict__ Xv,
    const void* __restrict__ Wq, const void* __restrict__ Wk, const void* __restrict__ Wv,
    const void* __restrict__ Bq, const void* __restrict__ Bk, const void* __restrict__ Bv,
    u16* __restrict__ Oq, u16* __restrict__ Ok, u16* __restrict__ Ov)
{
  __align__(16) __shared__ u16 As[4096];
  __align__(16) __shared__ u16 Bs[4096];
  const int z = blockIdx.z;
  const void* X  = (z == 0) ? Xq : (z == 1) ? Xk : Xv;
  const void* W  = (z == 0) ? Wq : (z == 1) ? Wk : Wv;
  const void* Bi = (z == 0) ? Bq : (z == 1) ? Bk : Bv;
  u16* O = (z == 0) ? Oq : (z == 1) ? Ok : Ov;
  const int aF32 = probe_is_f32(X);
  const int bF32 = probe_is_f32(W);
  const int cF32 = probe_is_f32(Bi);
  const int tid = threadIdx.x;
  const int m0 = blockIdx.y * 128, n0 = blockIdx.x * 128;
  floatx4 acc[4][4] = {};
  gemm_core_cvt(X, W, aF32, bF32, As, Bs, acc, m0, n0, 1024, tid);
  qkv_epilogue(acc, Bi, cF32, O, m0, n0, tid, z);
}

// ---------------------------------------------------------------------------
// Output projection: 128x128 tiles, grid (32 m, 8 n) XCD-swizzled, dbuf core.
// fp32 store to d_out.
// ---------------------------------------------------------------------------
__global__ __launch_bounds__(256) void out_gemm_bf16(
    const u16* __restrict__ X, const u16* __restrict__ W,
    const void* __restrict__ Bi, float* __restrict__ O)
{
  __align__(16) __shared__ u16 As[8192];
  __align__(16) __shared__ u16 Bs[8192];
  const int tid = threadIdx.x;
  const int m0 = blockIdx.x * 128, n0 = blockIdx.y * 128;
  floatx4 acc[4][4] = {};
  gemm_core_bf16(X, W, As, Bs, acc, m0, n0, 1024, tid);
  const int cF32 = probe_is_f32(Bi);
  const int lane = tid & 63, wv = tid >> 6;
  const int wm = wv >> 1, wn = wv & 1, g = lane >> 4, ml = lane & 15;
#pragma unroll
  for (int j = 0; j < 4; ++j) {
    int gn = n0 + wn * 64 + j * 16 + ml;
    float bvv = ldscalar(Bi, (size_t)gn, cF32);
#pragma unroll
    for (int i = 0; i < 4; ++i)
#pragma unroll
      for (int r = 0; r < 4; ++r) {
        int gm = m0 + wm * 64 + i * 16 + g * 4 + r;
        O[(size_t)gm * 1024 + gn] = acc[i][j][r] + bvv;
      }
  }
}

__global__ __launch_bounds__(256) void out_gemm_cvt(
    const u16* __restrict__ X, const void* __restrict__ W,
    const void* __restrict__ Bi, float* __restrict__ O)
{
  __align__(16) __shared__ u16 As[4096];
  __align__(16) __shared__ u16 Bs[4096];
  const int bF32 = probe_is_f32(W);
  const int cF32 = probe_is_f32(Bi);
  const int tid = threadIdx.x;
  const int m0 = blockIdx.y * 128, n0 = blockIdx.x * 128;
  floatx4 acc[4][4] = {};
  gemm_core_cvt(X, W, /*aF32=*/0, bF32, As, Bs, acc, m0, n0, 1024, tid);
  const int lane = tid & 63, wv = tid >> 6;
  const int wm = wv >> 1, wn = wv & 1, g = lane >> 4, ml = lane & 15;
#pragma unroll
  for (int j = 0; j < 4; ++j) {
    int gn = n0 + wn * 64 + j * 16 + ml;
    float bvv = ldscalar(Bi, (size_t)gn, cF32);
#pragma unroll
    for (int i = 0; i < 4; ++i)
#pragma unroll
      for (int r = 0; r < 4; ++r) {
        int gm = m0 + wm * 64 + i * 16 + g * 4 + r;
        O[(size_t)gm * 1024 + gn] = acc[i][j][r] + bvv;
      }
  }
}

// ---------------------------------------------------------------------------
// Flash attention v9: v8's 32x32x16 structure + SUBTILED LDS layout that is
// bank-conflict-free BY CONSTRUCTION.
// R3 post-mortem: v8's row-major [64][64-u16] tiles put every row start at
// bank 0 (128B rows); the 3-bit XOR couldn't spread 64 lanes over 32 rows x
// 2 chunks -> SQ_LDS_BANK_CONFLICT 4.19M, dur 62.7us.
// v9 layout: subtile (blk, ch) = rows 32blk..+31 x 16-u16 chunk ch, stored as
// [blk*4+ch][row][16] (1024B each). Every MFMA wave-read is then
// subtile_base + lane_slot*16B = ONE contiguous 1024B block (linear baseline,
// zero conflicts). Staging keeps linear global_load_lds destinations; the
// subtiling lives entirely in the per-lane GLOBAL source address (m173):
//   slot s = t*128+tid: blk=s>>8, ch=(s>>6)&3, row=(s>>1)&31, hh=s&1
//   K src: (32blk+row)*64 + 16ch + 8hh       (row = kv)
//   V src: (32blk+row)*2048 + 16ch + 8hh     (row = d, V is [B,H,D,S])
// Fragment reads (verified elementwise against MFMA A/B layouts):
//   QK^T A-frag: kb = Kc + (kvb*4+c)*512 + lq*16 + H*8  -> K[32kvb+lq][16c+8H+j]
//   PV   B-frag: vb = Vt + (db*4+c)*512 + lq*16 + H*8   -> V[16c+8H+j][32db+lq]
// Everything else (T12 transpose, mask, epilogue, K-dbuf counted-vmcnt
// pipeline) is byte-identical to v8 (which passed correctness).
// ---------------------------------------------------------------------------
__global__ __launch_bounds__(128) void flash_attn(
    const u16* __restrict__ Q, const u16* __restrict__ K, const u16* __restrict__ V,
    const int* __restrict__ Mask, u16* __restrict__ O)
{
  __align__(16) __shared__ u16 Ks[2][64 * 64];
  __align__(16) __shared__ u16 Vt[64 * 64];
  __align__(16) __shared__ int Ms[64];
  __shared__ int Wok[2];

  const int qt = blockIdx.x;
  const int bh = blockIdx.y;
  const int b = bh >> 4, h = bh & 15;
  const int tid = threadIdx.x;
  const int lane = tid & 63, wv = tid >> 6;
  const int H = lane >> 5, lq = lane & 31;
  const int koff = lq * 16 + H * 8;        // lane slot offset within a subtile

  const size_t baseQ  = (((size_t)b * 16 + h) * 2048 + (size_t)qt * 64) * 64;
  const size_t baseKV = ((size_t)b * 16 + h) * 2048 * 64;  // V is [B,H,D,S]

  {
    int la = 1;
#pragma unroll
    for (int i = 0; i < 16; ++i) la &= Mask[b * 2048 + tid * 16 + i];
    int wall = __all(la != 0);
    if (lane == 0) Wok[wv] = wall;
  }

  // Q fragments (B-operand): rows q = qt*64 + wv*32 + lq, d = 16c + 8H + j
  short8 qf[4];
  {
    const u16* qb = Q + baseQ + (size_t)(wv * 32 + lq) * 64 + H * 8;
#pragma unroll
    for (int c = 0; c < 4; ++c)
      qf[c] = *(const short8*)(qb + c * 16);
  }

  const u16* kg[4]; const u16* vg[4];
  int lo[4];
#pragma unroll
  for (int t = 0; t < 4; ++t) {
    int s = tid + t * 128;                  // 16B-slot 0..511 of the 8KB tile
    int blk = s >> 8;                       // 32-row block
    int ch  = (s >> 6) & 3;                 // 16-u16 chunk
    int row = (s >> 1) & 31;
    int hh  = s & 1;
    kg[t] = K + baseKV + (size_t)(blk * 32 + row) * 64 + ch * 16 + hh * 8;
    vg[t] = V + baseKV + (size_t)(blk * 32 + row) * 2048 + ch * 16 + hh * 8;
    lo[t] = ((tid & 64) + t * 128) * 8;     // wave-uniform base (u16 units)
  }

  // prologue: K tile 0 -> Ks[0]
#pragma unroll
  for (int t = 0; t < 4; ++t)
    __builtin_amdgcn_global_load_lds((const AS_GLOBAL unsigned int*)kg[t],
                                     (AS_LDS unsigned int*)(&Ks[0][0] + lo[t]), 16, 0, 0);

  __syncthreads();
  const bool maskall = Wok[0] && Wok[1];

  floatx16 oacc0 = {}, oacc1 = {};
  float lp = 0.f;

  int buf = 0;
#pragma unroll 2
  for (int kv0 = 0; kv0 < 2048; kv0 += 64) {
    // V(kv0) -> Vt (single-buffered; end-of-prev-iter barrier protects it)
#pragma unroll
    for (int t = 0; t < 4; ++t)
      __builtin_amdgcn_global_load_lds((const AS_GLOBAL unsigned int*)(vg[t] + kv0),
                                       (AS_LDS unsigned int*)(Vt + lo[t]), 16, 0, 0);
    // K(kv0+64) -> Ks[buf^1] (dummy wrap to tile 0 on last iter)
    const int nxt = (kv0 + 64) & 2047;
#pragma unroll
    for (int t = 0; t < 4; ++t)
      __builtin_amdgcn_global_load_lds((const AS_GLOBAL unsigned int*)(kg[t] + (size_t)nxt * 64),
                                       (AS_LDS unsigned int*)(&Ks[buf ^ 1][0] + lo[t]), 16, 0, 0);
    if (!maskall && tid < 64) Ms[tid] = Mask[b * 2048 + kv0 + tid];
    // K(kv0) landed (8 oldest done); 4V + 4K-prefetch stay in flight.
    __asm__ __volatile__("s_waitcnt vmcnt(8) lgkmcnt(0)\n\ts_barrier" ::: "memory");

    const u16* Kc = &Ks[buf][0];
    floatx16 a0 = {}, a1 = {};
    __builtin_amdgcn_s_setprio(1);
#pragma unroll
    for (int c = 0; c < 4; ++c) {
      short8 kb = *(const short8*)(Kc + c * 512 + koff);
      a0 = __builtin_amdgcn_mfma_f32_32x32x16_bf16(kb, qf[c], a0, 0, 0, 0);
    }
#pragma unroll
    for (int c = 0; c < 4; ++c) {
      short8 kb = *(const short8*)(Kc + (4 + c) * 512 + koff);
      a1 = __builtin_amdgcn_mfma_f32_32x32x16_bf16(kb, qf[c], a1, 0, 0, 0);
    }
    __builtin_amdgcn_s_setprio(0);

    float sv0[16], sv1[16];
#pragma unroll
    for (int r = 0; r < 16; ++r) { sv0[r] = a0[r]; sv1[r] = a1[r]; }
    if (!maskall) {
#pragma unroll
      for (int r = 0; r < 16; ++r) {
        int ko = (r & 3) + 8 * (r >> 2) + 4 * H;
        if (Ms[ko] == 0)      sv0[r] = -1.0e30f;
        if (Ms[32 + ko] == 0) sv1[r] = -1.0e30f;
      }
    }
#pragma unroll
    for (int r = 0; r < 16; ++r) {
      float p0 = __builtin_amdgcn_exp2f(sv0[r]);
      float p1 = __builtin_amdgcn_exp2f(sv1[r]);
      sv0[r] = p0; sv1[r] = p1;
      lp += p0 + p1;
    }

    // ---- in-register P transpose (T12 @ 32x32) ----
    unsigned int Wd0[8], Wd1[8];
#pragma unroll
    for (int i = 0; i < 8; ++i) {
      Wd0[i] = cvtpk_bf16(sv0[2 * i], sv0[2 * i + 1]);
      Wd1[i] = cvtpk_bf16(sv1[2 * i], sv1[2 * i + 1]);
    }
    short8 pa[4];
#define MAKE_PA(dst_, Wsrc_, base_) do {                                       \
    unsigned int u0 = Wsrc_[base_],     u1 = Wsrc_[(base_) + 1];               \
    unsigned int v0 = Wsrc_[(base_) + 2], v1 = Wsrc_[(base_) + 3];             \
    pl32_swap(u0, v0); pl32_swap(u1, v1);                                      \
    uint4v pw; pw[0] = u0; pw[1] = u1; pw[2] = v0; pw[3] = v1;                 \
    dst_ = __builtin_bit_cast(short8, pw);                                     \
  } while (0)
    MAKE_PA(pa[0], Wd0, 0);
    MAKE_PA(pa[1], Wd0, 4);
    MAKE_PA(pa[2], Wd1, 0);
    MAKE_PA(pa[3], Wd1, 4);
#undef MAKE_PA

    // V(kv0) landed; 4 K-prefetch stay in flight.
    __asm__ __volatile__("s_waitcnt vmcnt(4)\n\ts_barrier" ::: "memory");

    __builtin_amdgcn_s_setprio(1);
#pragma unroll
    for (int c = 0; c < 4; ++c) {
      short8 vb = *(const short8*)(Vt + c * 512 + koff);
      oacc0 = __builtin_amdgcn_mfma_f32_32x32x16_bf16(pa[c], vb, oacc0, 0, 0, 0);
    }
#pragma unroll
    for (int c = 0; c < 4; ++c) {
      short8 vb = *(const short8*)(Vt + (4 + c) * 512 + koff);
      oacc1 = __builtin_amdgcn_mfma_f32_32x32x16_bf16(pa[c], vb, oacc1, 0, 0, 0);
    }
    __builtin_amdgcn_s_setprio(0);

    // all waves done reading Ks[buf] + Vt -> safe to overwrite next iter
    __asm__ __volatile__("s_barrier" ::: "memory");
    buf ^= 1;
  }
  // drain dummy prefetch before epilogue / endpgm (LDS-dealloc hazard)
  __asm__ __volatile__("s_waitcnt vmcnt(0)" ::: "memory");

  // full row-sum for q = lq (H halves hold complementary kv sets)
  float l = lp + __shfl_xor(lp, 32);
  float inv = (l > 0.f) ? 1.0f / l : 0.f;

#pragma unroll
  for (int r = 0; r < 16; ++r) {
    int qo = (r & 3) + 8 * (r >> 2) + 4 * H;
    float ivr = __shfl(inv, qo);           // inv lives at lane qo (q-col = qo)
    int q = qt * 64 + wv * 32 + qo;
    size_t orow = ((size_t)b * 2048 + q) * 1024 + (size_t)h * 64;
    O[orow + lq]      = f2bf_fast(oacc0[r] * ivr);
    O[orow + 32 + lq] = f2bf_fast(oacc1[r] * ivr);
  }
}

// ---------------------------------------------------------------------------
extern "C" void kernel_launch(void* const* d_in, const int* in_sizes, int n_in,
                              void* d_out, int out_size, void* d_ws, size_t ws_size,
                              hipStream_t stream) {
  const void* q_in = d_in[0];
  const void* k_in = d_in[1];
  const void* v_in = d_in[2];
  const int* mask = (const int*)d_in[3];
  const void* Wq = d_in[4];  const void* bq = d_in[5];
  const void* Wk = d_in[6];  const void* bk = d_in[7];
  const void* Wv = d_in[8];  const void* bv = d_in[9];
  const void* Wo = d_in[10]; const void* bo = d_in[11];

  const size_t NTOK = (size_t)2 * 2048 * 1024;   // 4,194,304
  const size_t NW   = (size_t)1024 * 1024;       // 1,048,576

  if (ws_size >= (size_t)67108864) {
    u16* CXq = (u16*)d_ws;
    u16* CXk = CXq + NTOK;
    u16* CXv = CXk + NTOK;
    u16* CWq = CXv + NTOK;
    u16* CWk = CWq + NW;
    u16* CWv = CWk + NW;
    u16* CWo = CWv + NW;
    u16* Qp  = CWo + NW;
    u16* Kp  = Qp + NTOK;
    u16* Vp  = Kp + NTOK;   // [B,H,D,S]
    u16* Ao  = Vp + NTOK;

    cvt7<<<dim3(1024, 7), 256, 0, stream>>>(q_in, k_in, v_in, Wq, Wk, Wv, Wo,
                                            CXq, CXk, CXv, CWq, CWk, CWv, CWo);
    qkv_gemm_bf16<<<dim3(32, 8, 3), 256, 0, stream>>>(CXq, CXk, CXv,
                                                      CWq, CWk, CWv,
                                                      bq, bk, bv, Qp, Kp, Vp);
    flash_attn<<<dim3(32, 32), 128, 0, stream>>>(Qp, Kp, Vp, mask, Ao);
    out_gemm_bf16<<<dim3(32, 8), 256, 0, stream>>>(Ao, CWo, bo, (float*)d_out);
  } else {
    u16* Qp = (u16*)d_ws;
    u16* Kp = Qp + NTOK;
    u16* Vp = Kp + NTOK;    // [B,H,D,S]
    u16* Ao  = Vp + NTOK;

    qkv_gemm_cvt<<<dim3(8, 32, 3), 256, 0, stream>>>(q_in, k_in, v_in,
                                                     Wq, Wk, Wv, bq, bk, bv,
                                                     Qp, Kp, Vp);
    flash_attn<<<dim3(32, 32), 128, 0, stream>>>(Qp, Kp, Vp, mask, Ao);
    out_gemm_cvt<<<dim3(8, 32), 256, 0, stream>>>(Ao, Wo, bo, (float*)d_out);
  }
}

// Round 5
// 246.443 us; speedup vs baseline: 1.0245x; 1.0245x over previous
//
#include <hip/hip_runtime.h>
#include <stdint.h>

typedef unsigned short u16;
typedef __attribute__((ext_vector_type(8))) short short8;
typedef __attribute__((ext_vector_type(4))) short short4v;
typedef __attribute__((ext_vector_type(4))) float floatx4;
typedef __attribute__((ext_vector_type(16))) float floatx16;
typedef __attribute__((ext_vector_type(2))) unsigned int uint2v;
typedef __attribute__((ext_vector_type(4))) unsigned int uint4v;

#define AS_GLOBAL __attribute__((address_space(1)))
#define AS_LDS    __attribute__((address_space(3)))

// exp2 argument scale folded into Qp: 1/sqrt(1024) * log2(e)
#define QSCALE 0.045084220f

__device__ __forceinline__ float bf2f(u16 u) {
  union { unsigned int i; float f; } x; x.i = ((unsigned int)u) << 16; return x.f;
}
__device__ __forceinline__ u16 f2bf(float f) {          // RNE
  union { float f; unsigned int i; } x; x.f = f;
  unsigned int u = x.i;
  u += 0x7fffu + ((u >> 16) & 1u);
  return (u16)(u >> 16);
}
__device__ __forceinline__ u16 f2bf_fast(float f) {     // round-half-up, 2 ops
  union { float f; unsigned int i; } x; x.f = f;
  return (u16)((x.i + 0x8000u) >> 16);
}

// pack two f32 -> bf16x2 word (v_cvt_pk_bf16_f32: lo -> [15:0], hi -> [31:16])
__device__ __forceinline__ unsigned int cvtpk_bf16(float lo, float hi) {
  unsigned int w;
  __asm__("v_cvt_pk_bf16_f32 %0, %1, %2" : "=v"(w) : "v"(lo), "v"(hi));
  return w;
}

// paired half-swap (gfx950): a' = {a.lo, b.lo}, b' = {a.hi, b.hi}
__device__ __forceinline__ void pl32_swap(unsigned int& a, unsigned int& b) {
#if __has_builtin(__builtin_amdgcn_permlane32_swap)
  uint2v r = __builtin_amdgcn_permlane32_swap(a, b, false, false);
  a = r[0]; b = r[1];
#else
  __asm__("v_permlane32_swap_b32 %0, %1" : "+v"(a), "+v"(b));
#endif
}

// Runtime dtype probe (R4-validated).
__device__ __forceinline__ int probe_is_f32(const void* p) {
  const unsigned int* w = (const unsigned int*)p;
  int cnt = 0;
#pragma unroll
  for (int i = 0; i < 64; ++i) {
    unsigned int lo = w[i] & 0xFFFFu;
    int e = (int)((lo >> 7) & 0xFFu);
    cnt += (e >= 117 && e <= 137) ? 1 : 0;
  }
  return cnt < 32;
}

__device__ __forceinline__ short8 ld8(const void* P, size_t off, int isf32) {
  if (isf32) {
    const float* q = (const float*)P + off;
    float4 x = *(const float4*)q;
    float4 y = *(const float4*)(q + 4);
    short8 r;
    r[0] = (short)f2bf(x.x); r[1] = (short)f2bf(x.y);
    r[2] = (short)f2bf(x.z); r[3] = (short)f2bf(x.w);
    r[4] = (short)f2bf(y.x); r[5] = (short)f2bf(y.y);
    r[6] = (short)f2bf(y.z); r[7] = (short)f2bf(y.w);
    return r;
  }
  return *(const short8*)((const u16*)P + off);
}

__device__ __forceinline__ float ldscalar(const void* P, size_t idx, int isf32) {
  return isf32 ? ((const float*)P)[idx] : bf2f(((const u16*)P)[idx]);
}

// ---------------------------------------------------------------------------
// cvt7: one-shot fp32->bf16 of 3 X tensors + 4 W tensors. grid (1024, 7).
// ---------------------------------------------------------------------------
__global__ __launch_bounds__(256) void cvt7(
    const void* s0, const void* s1, const void* s2, const void* s3,
    const void* s4, const void* s5, const void* s6,
    u16* d0, u16* d1, u16* d2, u16* d3, u16* d4, u16* d5, u16* d6)
{
  const int z = blockIdx.y;
  const void* src; u16* dst; int n;
  switch (z) {
    case 0: src = s0; dst = d0; n = 4194304; break;
    case 1: src = s1; dst = d1; n = 4194304; break;
    case 2: src = s2; dst = d2; n = 4194304; break;
    case 3: src = s3; dst = d3; n = 1048576; break;
    case 4: src = s4; dst = d4; n = 1048576; break;
    case 5: src = s5; dst = d5; n = 1048576; break;
    default: src = s6; dst = d6; n = 1048576; break;
  }
  const int isf32 = probe_is_f32(src);
  for (int i = blockIdx.x * 256 + threadIdx.x; i * 4 < n; i += gridDim.x * 256) {
    if (isf32) {
      float4 x = ((const float4*)src)[i];
      short4v r;
      r[0] = (short)f2bf(x.x); r[1] = (short)f2bf(x.y);
      r[2] = (short)f2bf(x.z); r[3] = (short)f2bf(x.w);
      *(short4v*)(dst + (size_t)i * 4) = r;
    } else {
      *(short4v*)(dst + (size_t)i * 4) = ((const short4v*)src)[i];
    }
  }
}

// ---------------------------------------------------------------------------
// bf16 MFMA GEMM core v3: BK=32 + DOUBLE-BUFFERED LDS with raw-asm barriers.
// Prefetch for tile k+1 is issued BEFORE the barrier and stays in flight
// across it (s_waitcnt vmcnt(4), never 0 inside the loop).
// As/Bs must each be 8192 u16 (two 4096 buffers). 128x128 tile, 4 waves.
// ---------------------------------------------------------------------------
__device__ __forceinline__ void gemm_core_bf16(
    const u16* __restrict__ A, const u16* __restrict__ W,
    u16* As, u16* Bs, floatx4 acc[4][4], int m0, int n0, int K, int tid)
{
  const int lane = tid & 63, wv = tid >> 6;
  const int wm = wv >> 1, wn = wv & 1;
  const int g = lane >> 4, ml = lane & 15;
  const int r0 = tid >> 2, kc = (tid & 3) << 3;
  const u16* Ag0 = A + (size_t)(m0 + r0) * K + kc;
  const u16* Ag1 = A + (size_t)(m0 + r0 + 64) * K + kc;
  const u16* Bg0 = W + (size_t)(n0 + r0) * K + kc;
  const u16* Bg1 = W + (size_t)(n0 + r0 + 64) * K + kc;

#define STAGE_QKV(buf_, kt_) do {                                              \
    u16* a0 = As + (buf_) * 4096 + tid * 8;                                    \
    u16* b0 = Bs + (buf_) * 4096 + tid * 8;                                    \
    __builtin_amdgcn_global_load_lds((const AS_GLOBAL unsigned int*)(Ag0 + (kt_)), \
                                     (AS_LDS unsigned int*)a0, 16, 0, 0);      \
    __builtin_amdgcn_global_load_lds((const AS_GLOBAL unsigned int*)(Ag1 + (kt_)), \
                                     (AS_LDS unsigned int*)(a0 + 2048), 16, 0, 0); \
    __builtin_amdgcn_global_load_lds((const AS_GLOBAL unsigned int*)(Bg0 + (kt_)), \
                                     (AS_LDS unsigned int*)b0, 16, 0, 0);      \
    __builtin_amdgcn_global_load_lds((const AS_GLOBAL unsigned int*)(Bg1 + (kt_)), \
                                     (AS_LDS unsigned int*)(b0 + 2048), 16, 0, 0); \
  } while (0)

  STAGE_QKV(0, 0);
  int buf = 0;
#pragma unroll 2
  for (int kt = 0; kt < K; kt += 32) {
    const int nk = (kt + 32 < K) ? (kt + 32) : 0;   // dummy reload on last iter
    STAGE_QKV(buf ^ 1, nk);
    // wait current tile (4 oldest), keep prefetch (4 newest) in flight
    __asm__ __volatile__("s_waitcnt vmcnt(4)\n\ts_barrier" ::: "memory");
    const u16* Ac = As + buf * 4096;
    const u16* Bc = Bs + buf * 4096;
    short8 af[4], bf[4];
#pragma unroll
    for (int i = 0; i < 4; ++i)
      af[i] = *(const short8*)(Ac + (wm * 64 + i * 16 + ml) * 32 + g * 8);
#pragma unroll
    for (int j = 0; j < 4; ++j)
      bf[j] = *(const short8*)(Bc + (wn * 64 + j * 16 + ml) * 32 + g * 8);
#pragma unroll
    for (int i = 0; i < 4; ++i)
#pragma unroll
      for (int j = 0; j < 4; ++j)
        acc[i][j] = __builtin_amdgcn_mfma_f32_16x16x32_bf16(af[i], bf[j], acc[i][j], 0, 0, 0);
    // all waves done reading buf before it becomes next prefetch target
    __asm__ __volatile__("s_waitcnt lgkmcnt(0)\n\ts_barrier" ::: "memory");
    buf ^= 1;
  }
#undef STAGE_QKV
  // drain dummy prefetch before epilogue / endpgm (LDS-dealloc hazard)
  __asm__ __volatile__("s_waitcnt vmcnt(0)" ::: "memory");
}

// R7-proven fallback core: BK=32, cvt-in-staging. (As/Bs = 4096 u16)
__device__ __forceinline__ void gemm_core_cvt(
    const void* __restrict__ A, const void* __restrict__ W, int aF32, int bF32,
    u16* As, u16* Bs, floatx4 acc[4][4], int m0, int n0, int K, int tid)
{
  const int lane = tid & 63, wv = tid >> 6;
  const int wm = wv >> 1, wn = wv & 1;
  const int g = lane >> 4, ml = lane & 15;
  const int r0 = tid >> 2, kc = (tid & 3) << 3;
  const size_t offA0 = (size_t)(m0 + r0) * K + kc;
  const size_t offA1 = (size_t)(m0 + r0 + 64) * K + kc;
  const size_t offB0 = (size_t)(n0 + r0) * K + kc;
  const size_t offB1 = (size_t)(n0 + r0 + 64) * K + kc;
  u16* Al0 = As + tid * 8;  u16* Al1 = As + (tid + 256) * 8;
  u16* Bl0 = Bs + tid * 8;  u16* Bl1 = Bs + (tid + 256) * 8;
  for (int kt = 0; kt < K; kt += 32) {
    short8 a0 = ld8(A, offA0 + kt, aF32);
    short8 a1 = ld8(A, offA1 + kt, aF32);
    short8 b0 = ld8(W, offB0 + kt, bF32);
    short8 b1 = ld8(W, offB1 + kt, bF32);
    *(short8*)Al0 = a0;  *(short8*)Al1 = a1;
    *(short8*)Bl0 = b0;  *(short8*)Bl1 = b1;
    __syncthreads();
    short8 af[4], bf[4];
#pragma unroll
    for (int i = 0; i < 4; ++i)
      af[i] = *(const short8*)(As + (wm * 64 + i * 16 + ml) * 32 + g * 8);
#pragma unroll
    for (int j = 0; j < 4; ++j)
      bf[j] = *(const short8*)(Bs + (wn * 64 + j * 16 + ml) * 32 + g * 8);
#pragma unroll
    for (int i = 0; i < 4; ++i)
#pragma unroll
      for (int j = 0; j < 4; ++j)
        acc[i][j] = __builtin_amdgcn_mfma_f32_16x16x32_bf16(af[i], bf[j], acc[i][j], 0, 0, 0);
    __syncthreads();
  }
}

// ---------------------------------------------------------------------------
// QKV epilogue: z=0 (Q) scaled by QSCALE into [B,H,S,D]; z=1 (K) [B,H,S,D];
// z=2 (V) TRANSPOSED into [B,H,D,S] (4-wide packed along s).
// ---------------------------------------------------------------------------
__device__ __forceinline__ void qkv_epilogue(
    floatx4 acc[4][4], const void* Bi, int cF32, u16* O, int m0, int n0,
    int tid, int z)
{
  const int lane = tid & 63, wv = tid >> 6;
  const int wm = wv >> 1, wn = wv & 1, g = lane >> 4, ml = lane & 15;
  const float sc = (z == 0) ? QSCALE : 1.0f;
#pragma unroll
  for (int j = 0; j < 4; ++j) {
    int gn = n0 + wn * 64 + j * 16 + ml;
    float bvv = ldscalar(Bi, (size_t)gn, cF32);
    int h = gn >> 6, d = gn & 63;
    if (z == 2) {
#pragma unroll
      for (int i = 0; i < 4; ++i) {
        int gm0 = m0 + wm * 64 + i * 16 + g * 4;
        int b = gm0 >> 11, s0 = gm0 & 2047;
        short4v pk;
#pragma unroll
        for (int r = 0; r < 4; ++r) pk[r] = (short)f2bf_fast(acc[i][j][r] + bvv);
        *(short4v*)(O + ((((size_t)b * 16 + h) * 64 + d) * 2048 + s0)) = pk;
      }
    } else {
#pragma unroll
      for (int i = 0; i < 4; ++i)
#pragma unroll
        for (int r = 0; r < 4; ++r) {
          int gm = m0 + wm * 64 + i * 16 + g * 4 + r;
          int b = gm >> 11, s = gm & 2047;
          O[(((size_t)b * 16 + h) * 2048 + s) * 64 + d] =
              f2bf_fast((acc[i][j][r] + bvv) * sc);
        }
    }
  }
}

// grid (32 m-tiles, 8 n-tiles, 3): linear index ≡ m (mod 8) -> XCD keeps a
// fixed quarter of A's rows hot and reuses each W tile 4x in its own L2.
__global__ __launch_bounds__(256) void qkv_gemm_bf16(
    const u16* __restrict__ Xq, const u16* __restrict__ Xk, const u16* __restrict__ Xv,
    const u16* __restrict__ Wq, const u16* __restrict__ Wk, const u16* __restrict__ Wv,
    const void* __restrict__ Bq, const void* __restrict__ Bk, const void* __restrict__ Bv,
    u16* __restrict__ Oq, u16* __restrict__ Ok, u16* __restrict__ Ov)
{
  __align__(16) __shared__ u16 As[8192];
  __align__(16) __shared__ u16 Bs[8192];
  const int z = blockIdx.z;
  const u16* X = (z == 0) ? Xq : (z == 1) ? Xk : Xv;
  const u16* W = (z == 0) ? Wq : (z == 1) ? Wk : Wv;
  const void* Bi = (z == 0) ? Bq : (z == 1) ? Bk : Bv;
  u16* O = (z == 0) ? Oq : (z == 1) ? Ok : Ov;
  const int tid = threadIdx.x;
  const int m0 = blockIdx.x * 128, n0 = blockIdx.y * 128;
  floatx4 acc[4][4] = {};
  gemm_core_bf16(X, W, As, Bs, acc, m0, n0, 1024, tid);
  const int cF32 = probe_is_f32(Bi);   // after core: no stray vmem in loop
  qkv_epilogue(acc, Bi, cF32, O, m0, n0, tid, z);
}

__global__ __launch_bounds__(256) void qkv_gemm_cvt(
    const void* __restrict__ Xq, const void* __restrict__ Xk, const void* __restrict__ Xv,
    const void* __restrict__ Wq, const void* __restrict__ Wk, const void* __restrict__ Wv,
    const void* __restrict__ Bq, const void* __restrict__ Bk, const void* __restrict__ Bv,
    u16* __restrict__ Oq, u16* __restrict__ Ok, u16* __restrict__ Ov)
{
  __align__(16) __shared__ u16 As[4096];
  __align__(16) __shared__ u16 Bs[4096];
  const int z = blockIdx.z;
  const void* X  = (z == 0) ? Xq : (z == 1) ? Xk : Xv;
  const void* W  = (z == 0) ? Wq : (z == 1) ? Wk : Wv;
  const void* Bi = (z == 0) ? Bq : (z == 1) ? Bk : Bv;
  u16* O = (z == 0) ? Oq : (z == 1) ? Ok : Ov;
  const int aF32 = probe_is_f32(X);
  const int bF32 = probe_is_f32(W);
  const int cF32 = probe_is_f32(Bi);
  const int tid = threadIdx.x;
  const int m0 = blockIdx.y * 128, n0 = blockIdx.x * 128;
  floatx4 acc[4][4] = {};
  gemm_core_cvt(X, W, aF32, bF32, As, Bs, acc, m0, n0, 1024, tid);
  qkv_epilogue(acc, Bi, cF32, O, m0, n0, tid, z);
}

// ---------------------------------------------------------------------------
// Output projection: 128x128 tiles, grid (32 m, 8 n) XCD-swizzled, dbuf core.
// fp32 store to d_out.
// ---------------------------------------------------------------------------
__global__ __launch_bounds__(256) void out_gemm_bf16(
    const u16* __restrict__ X, const u16* __restrict__ W,
    const void* __restrict__ Bi, float* __restrict__ O)
{
  __align__(16) __shared__ u16 As[8192];
  __align__(16) __shared__ u16 Bs[8192];
  const int tid = threadIdx.x;
  const int m0 = blockIdx.x * 128, n0 = blockIdx.y * 128;
  floatx4 acc[4][4] = {};
  gemm_core_bf16(X, W, As, Bs, acc, m0, n0, 1024, tid);
  const int cF32 = probe_is_f32(Bi);
  const int lane = tid & 63, wv = tid >> 6;
  const int wm = wv >> 1, wn = wv & 1, g = lane >> 4, ml = lane & 15;
#pragma unroll
  for (int j = 0; j < 4; ++j) {
    int gn = n0 + wn * 64 + j * 16 + ml;
    float bvv = ldscalar(Bi, (size_t)gn, cF32);
#pragma unroll
    for (int i = 0; i < 4; ++i)
#pragma unroll
      for (int r = 0; r < 4; ++r) {
        int gm = m0 + wm * 64 + i * 16 + g * 4 + r;
        O[(size_t)gm * 1024 + gn] = acc[i][j][r] + bvv;
      }
  }
}

__global__ __launch_bounds__(256) void out_gemm_cvt(
    const u16* __restrict__ X, const void* __restrict__ W,
    const void* __restrict__ Bi, float* __restrict__ O)
{
  __align__(16) __shared__ u16 As[4096];
  __align__(16) __shared__ u16 Bs[4096];
  const int bF32 = probe_is_f32(W);
  const int cF32 = probe_is_f32(Bi);
  const int tid = threadIdx.x;
  const int m0 = blockIdx.y * 128, n0 = blockIdx.x * 128;
  floatx4 acc[4][4] = {};
  gemm_core_cvt(X, W, /*aF32=*/0, bF32, As, Bs, acc, m0, n0, 1024, tid);
  const int lane = tid & 63, wv = tid >> 6;
  const int wm = wv >> 1, wn = wv & 1, g = lane >> 4, ml = lane & 15;
#pragma unroll
  for (int j = 0; j < 4; ++j) {
    int gn = n0 + wn * 64 + j * 16 + ml;
    float bvv = ldscalar(Bi, (size_t)gn, cF32);
#pragma unroll
    for (int i = 0; i < 4; ++i)
#pragma unroll
      for (int r = 0; r < 4; ++r) {
        int gm = m0 + wm * 64 + i * 16 + g * 4 + r;
        O[(size_t)gm * 1024 + gn] = acc[i][j][r] + bvv;
      }
  }
}

// ---------------------------------------------------------------------------
// Flash attention v10: v9's math (32x32 MFMA + subtiled conflict-free LDS +
// T12 in-register transpose) with FOUR waves per block, each owning a
// (q-half x kv-half) quadrant of the 64x64 tile.
// R4 post-mortem: SQ_LDS_BANK_CONFLICT identical (exactly 2^22) across two
// different read layouts -> it's a fixed +4cyc/ds_read_b128 artifact, not a
// lever; LDS BW was never binding. v8/v9's 62us is issue/latency-bound at
// 2 waves/SIMD (MfmaUtil 22% == exactly the 13.7us MFMA-pipe demand).
// v10 halves per-wave work and doubles waves/CU to 16 (4/SIMD, enforced by
// __launch_bounds__(256,4); est ~100 VGPR).
// kv-split legality: no-max softmax partials are additive; each wave keeps
// lp/oacc over its kv-half, combined once at the end via the (dead) Ks LDS:
// each wave deposits the d-half it does NOT store, partner adds + stores.
// Wave wv: qh=wv&1 (q rows 32qh..+31), kh=wv>>1 (kv 32kh..+31).
// Per iter per wave: 4 QK-MFMA (chained) + softmax(16) + transpose(8 cvtpk,
// 4 pl32) + 4 PV-MFMA. Staging: per wave 2 V-gll + 2 K-gll -> vmcnt(4)/(2).
// ---------------------------------------------------------------------------
__global__ __launch_bounds__(256, 4) void flash_attn(
    const u16* __restrict__ Q, const u16* __restrict__ K, const u16* __restrict__ V,
    const int* __restrict__ Mask, u16* __restrict__ O)
{
  __align__(16) __shared__ u16 Ks[2][64 * 64];   // doubles as f32 exchange buf
  __align__(16) __shared__ u16 Vt[64 * 64];
  __align__(16) __shared__ int Ms[64];
  __align__(16) __shared__ float Lf[256];
  __shared__ int Wok[4];

  const int qt = blockIdx.x;
  const int bh = blockIdx.y;
  const int b = bh >> 4, h = bh & 15;
  const int tid = threadIdx.x;
  const int lane = tid & 63, wv = tid >> 6;
  const int qh = wv & 1, kh = wv >> 1;
  const int H = lane >> 5, lq = lane & 31;
  const int koff = lq * 16 + H * 8;        // lane slot offset within a subtile

  const size_t baseQ  = (((size_t)b * 16 + h) * 2048 + (size_t)qt * 64) * 64;
  const size_t baseKV = ((size_t)b * 16 + h) * 2048 * 64;  // V is [B,H,D,S]

  {
    int la = 1;
#pragma unroll
    for (int i = 0; i < 8; ++i) la &= Mask[b * 2048 + tid * 8 + i];
    int wall = __all(la != 0);
    if (lane == 0) Wok[wv] = wall;
  }

  // Q fragments (B-operand): rows q = qt*64 + qh*32 + lq, d = 16c + 8H + j
  short8 qf[4];
  {
    const u16* qb = Q + baseQ + (size_t)(qh * 32 + lq) * 64 + H * 8;
#pragma unroll
    for (int c = 0; c < 4; ++c)
      qf[c] = *(const short8*)(qb + c * 16);
  }

  // staging: 512 16B-slots over 256 threads x 2; subtile encoding in the
  // global source address, linear LDS dest (m173 pattern).
  const u16* kg[2]; const u16* vg[2];
  int lo[2];
#pragma unroll
  for (int t = 0; t < 2; ++t) {
    int s = tid + t * 256;
    int blk = s >> 8;                       // 32-row block
    int ch  = (s >> 6) & 3;                 // 16-u16 chunk
    int row = (s >> 1) & 31;
    int hh  = s & 1;
    kg[t] = K + baseKV + (size_t)(blk * 32 + row) * 64 + ch * 16 + hh * 8;
    vg[t] = V + baseKV + (size_t)(blk * 32 + row) * 2048 + ch * 16 + hh * 8;
    lo[t] = ((tid & 192) + t * 256) * 8;    // wave-uniform base (u16 units)
  }

  // prologue: K tile 0 -> Ks[0]
#pragma unroll
  for (int t = 0; t < 2; ++t)
    __builtin_amdgcn_global_load_lds((const AS_GLOBAL unsigned int*)kg[t],
                                     (AS_LDS unsigned int*)(&Ks[0][0] + lo[t]), 16, 0, 0);

  __syncthreads();
  const bool maskall = Wok[0] && Wok[1] && Wok[2] && Wok[3];

  floatx16 oacc0 = {}, oacc1 = {};
  float lp = 0.f;

  int buf = 0;
#pragma unroll 2
  for (int kv0 = 0; kv0 < 2048; kv0 += 64) {
    // V(kv0) -> Vt (single-buffered; end-of-prev-iter barrier protects it)
#pragma unroll
    for (int t = 0; t < 2; ++t)
      __builtin_amdgcn_global_load_lds((const AS_GLOBAL unsigned int*)(vg[t] + kv0),
                                       (AS_LDS unsigned int*)(Vt + lo[t]), 16, 0, 0);
    // K(kv0+64) -> Ks[buf^1] (dummy wrap to tile 0 on last iter)
    const int nxt = (kv0 + 64) & 2047;
#pragma unroll
    for (int t = 0; t < 2; ++t)
      __builtin_amdgcn_global_load_lds((const AS_GLOBAL unsigned int*)(kg[t] + (size_t)nxt * 64),
                                       (AS_LDS unsigned int*)(&Ks[buf ^ 1][0] + lo[t]), 16, 0, 0);
    if (!maskall && tid < 64) Ms[tid] = Mask[b * 2048 + kv0 + tid];
    // per-wave queue: [K(kv0) 2 | V(kv0) 2 | K(next) 2] -> vmcnt(4) waits K(kv0)
    __asm__ __volatile__("s_waitcnt vmcnt(4) lgkmcnt(0)\n\ts_barrier" ::: "memory");

    const u16* Kc = &Ks[buf][0];
    floatx16 a = {};
    __builtin_amdgcn_s_setprio(1);
#pragma unroll
    for (int c = 0; c < 4; ++c) {
      short8 kb = *(const short8*)(Kc + (kh * 4 + c) * 512 + koff);
      a = __builtin_amdgcn_mfma_f32_32x32x16_bf16(kb, qf[c], a, 0, 0, 0);
    }
    __builtin_amdgcn_s_setprio(0);

    float sv[16];
#pragma unroll
    for (int r = 0; r < 16; ++r) sv[r] = a[r];
    if (!maskall) {
#pragma unroll
      for (int r = 0; r < 16; ++r) {
        int ko = 32 * kh + (r & 3) + 8 * (r >> 2) + 4 * H;
        if (Ms[ko] == 0) sv[r] = -1.0e30f;
      }
    }
#pragma unroll
    for (int r = 0; r < 16; ++r) {
      float p = __builtin_amdgcn_exp2f(sv[r]);
      sv[r] = p;
      lp += p;
    }

    // ---- in-register P transpose (T12 @ 32x32, one kv-block) ----
    unsigned int Wd[8];
#pragma unroll
    for (int i = 0; i < 8; ++i)
      Wd[i] = cvtpk_bf16(sv[2 * i], sv[2 * i + 1]);
    short8 pa[2];
#define MAKE_PA(dst_, Wsrc_, base_) do {                                       \
    unsigned int u0 = Wsrc_[base_],       u1 = Wsrc_[(base_) + 1];             \
    unsigned int v0 = Wsrc_[(base_) + 2], v1 = Wsrc_[(base_) + 3];             \
    pl32_swap(u0, v0); pl32_swap(u1, v1);                                      \
    uint4v pw; pw[0] = u0; pw[1] = u1; pw[2] = v0; pw[3] = v1;                 \
    dst_ = __builtin_bit_cast(short8, pw);                                     \
  } while (0)
    MAKE_PA(pa[0], Wd, 0);
    MAKE_PA(pa[1], Wd, 4);
#undef MAKE_PA

    // V(kv0) landed; 2 K-prefetch stay in flight.
    __asm__ __volatile__("s_waitcnt vmcnt(2)\n\ts_barrier" ::: "memory");

    __builtin_amdgcn_s_setprio(1);
#pragma unroll
    for (int c = 0; c < 2; ++c) {
      short8 vb = *(const short8*)(Vt + (2 * kh + c) * 512 + koff);           // db=0
      oacc0 = __builtin_amdgcn_mfma_f32_32x32x16_bf16(pa[c], vb, oacc0, 0, 0, 0);
    }
#pragma unroll
    for (int c = 0; c < 2; ++c) {
      short8 vb = *(const short8*)(Vt + (4 + 2 * kh + c) * 512 + koff);      // db=1
      oacc1 = __builtin_amdgcn_mfma_f32_32x32x16_bf16(pa[c], vb, oacc1, 0, 0, 0);
    }
    __builtin_amdgcn_s_setprio(0);

    // all waves done reading Ks[buf] + Vt -> safe to overwrite next iter
    __asm__ __volatile__("s_barrier" ::: "memory");
    buf ^= 1;
  }
  // drain dummy prefetch; barrier before reusing Ks as the exchange buffer
  __asm__ __volatile__("s_waitcnt vmcnt(0)" ::: "memory");
  __syncthreads();

  // ---- cross-wave (kh) combine ----
  // l: in-wave H-combine, then exchange with partner wave (wv ^ 2)
  float lh = lp + __shfl_xor(lp, 32);
  Lf[wv * 64 + lane] = lh;
  // O partials: deposit the d-half this wave will NOT store.
  // Region per wave: 1024 floats at Xf + wv*1024; chunk layout w*256 + lane*4
  // (lane-contiguous float4s -> conflict-free).
  float* Xf = (float*)&Ks[0][0];
  {
    float* myreg = Xf + wv * 1024;
    const floatx16& dep = kh ? oacc0 : oacc1;   // kh0 deposits d-high, kh1 d-low
#pragma unroll
    for (int w = 0; w < 4; ++w) {
      float4 f4;
      f4.x = dep[4 * w + 0]; f4.y = dep[4 * w + 1];
      f4.z = dep[4 * w + 2]; f4.w = dep[4 * w + 3];
      *(float4*)(myreg + w * 256 + lane * 4) = f4;
    }
  }
  __syncthreads();
  const int pwv = wv ^ 2;
  float l = lh + Lf[pwv * 64 + lane];
  float inv = (l > 0.f) ? 1.0f / l : 0.f;
  floatx16 mine = kh ? oacc1 : oacc0;           // the d-half this wave stores
  {
    const float* prr = Xf + pwv * 1024;
#pragma unroll
    for (int w = 0; w < 4; ++w) {
      float4 f4 = *(const float4*)(prr + w * 256 + lane * 4);
      mine[4 * w + 0] += f4.x; mine[4 * w + 1] += f4.y;
      mine[4 * w + 2] += f4.z; mine[4 * w + 3] += f4.w;
    }
  }

#pragma unroll
  for (int r = 0; r < 16; ++r) {
    int qo = (r & 3) + 8 * (r >> 2) + 4 * H;
    float ivr = __shfl(inv, qo);           // inv lives at lane qo (q-col = qo)
    int q = qt * 64 + qh * 32 + qo;
    size_t orow = ((size_t)b * 2048 + q) * 1024 + (size_t)h * 64;
    O[orow + kh * 32 + lq] = f2bf_fast(mine[r] * ivr);
  }
}

// ---------------------------------------------------------------------------
extern "C" void kernel_launch(void* const* d_in, const int* in_sizes, int n_in,
                              void* d_out, int out_size, void* d_ws, size_t ws_size,
                              hipStream_t stream) {
  const void* q_in = d_in[0];
  const void* k_in = d_in[1];
  const void* v_in = d_in[2];
  const int* mask = (const int*)d_in[3];
  const void* Wq = d_in[4];  const void* bq = d_in[5];
  const void* Wk = d_in[6];  const void* bk = d_in[7];
  const void* Wv = d_in[8];  const void* bv = d_in[9];
  const void* Wo = d_in[10]; const void* bo = d_in[11];

  const size_t NTOK = (size_t)2 * 2048 * 1024;   // 4,194,304
  const size_t NW   = (size_t)1024 * 1024;       // 1,048,576

  if (ws_size >= (size_t)67108864) {
    u16* CXq = (u16*)d_ws;
    u16* CXk = CXq + NTOK;
    u16* CXv = CXk + NTOK;
    u16* CWq = CXv + NTOK;
    u16* CWk = CWq + NW;
    u16* CWv = CWk + NW;
    u16* CWo = CWv + NW;
    u16* Qp  = CWo + NW;
    u16* Kp  = Qp + NTOK;
    u16* Vp  = Kp + NTOK;   // [B,H,D,S]
    u16* Ao  = Vp + NTOK;

    cvt7<<<dim3(1024, 7), 256, 0, stream>>>(q_in, k_in, v_in, Wq, Wk, Wv, Wo,
                                            CXq, CXk, CXv, CWq, CWk, CWv, CWo);
    qkv_gemm_bf16<<<dim3(32, 8, 3), 256, 0, stream>>>(CXq, CXk, CXv,
                                                      CWq, CWk, CWv,
                                                      bq, bk, bv, Qp, Kp, Vp);
    flash_attn<<<dim3(32, 32), 256, 0, stream>>>(Qp, Kp, Vp, mask, Ao);
    out_gemm_bf16<<<dim3(32, 8), 256, 0, stream>>>(Ao, CWo, bo, (float*)d_out);
  } else {
    u16* Qp = (u16*)d_ws;
    u16* Kp = Qp + NTOK;
    u16* Vp = Kp + NTOK;    // [B,H,D,S]
    u16* Ao  = Vp + NTOK;

    qkv_gemm_cvt<<<dim3(8, 32, 3), 256, 0, stream>>>(q_in, k_in, v_in,
                                                     Wq, Wk, Wv, bq, bk, bv,
                                                     Qp, Kp, Vp);
    flash_attn<<<dim3(32, 32), 256, 0, stream>>>(Qp, Kp, Vp, mask, Ao);
    out_gemm_cvt<<<dim3(8, 32), 256, 0, stream>>>(Ao, Wo, bo, (float*)d_out);
  }
}

// Round 6
// 240.700 us; speedup vs baseline: 1.0490x; 1.0239x over previous
//
#include <hip/hip_runtime.h>
#include <stdint.h>

typedef unsigned short u16;
typedef __attribute__((ext_vector_type(8))) short short8;
typedef __attribute__((ext_vector_type(4))) short short4v;
typedef __attribute__((ext_vector_type(4))) float floatx4;
typedef __attribute__((ext_vector_type(16))) float floatx16;
typedef __attribute__((ext_vector_type(2))) unsigned int uint2v;
typedef __attribute__((ext_vector_type(4))) unsigned int uint4v;

#define AS_GLOBAL __attribute__((address_space(1)))
#define AS_LDS    __attribute__((address_space(3)))

// exp2 argument scale folded into Qp: 1/sqrt(1024) * log2(e)
#define QSCALE 0.045084220f

__device__ __forceinline__ float bf2f(u16 u) {
  union { unsigned int i; float f; } x; x.i = ((unsigned int)u) << 16; return x.f;
}
__device__ __forceinline__ u16 f2bf(float f) {          // RNE
  union { float f; unsigned int i; } x; x.f = f;
  unsigned int u = x.i;
  u += 0x7fffu + ((u >> 16) & 1u);
  return (u16)(u >> 16);
}
__device__ __forceinline__ u16 f2bf_fast(float f) {     // round-half-up, 2 ops
  union { float f; unsigned int i; } x; x.f = f;
  return (u16)((x.i + 0x8000u) >> 16);
}

// pack two f32 -> bf16x2 word (v_cvt_pk_bf16_f32: lo -> [15:0], hi -> [31:16])
__device__ __forceinline__ unsigned int cvtpk_bf16(float lo, float hi) {
  unsigned int w;
  __asm__("v_cvt_pk_bf16_f32 %0, %1, %2" : "=v"(w) : "v"(lo), "v"(hi));
  return w;
}

// paired half-swap (gfx950): a' = {a.lo, b.lo}, b' = {a.hi, b.hi}
__device__ __forceinline__ void pl32_swap(unsigned int& a, unsigned int& b) {
#if __has_builtin(__builtin_amdgcn_permlane32_swap)
  uint2v r = __builtin_amdgcn_permlane32_swap(a, b, false, false);
  a = r[0]; b = r[1];
#else
  __asm__("v_permlane32_swap_b32 %0, %1" : "+v"(a), "+v"(b));
#endif
}

// Runtime dtype probe (R4-validated).
__device__ __forceinline__ int probe_is_f32(const void* p) {
  const unsigned int* w = (const unsigned int*)p;
  int cnt = 0;
#pragma unroll
  for (int i = 0; i < 64; ++i) {
    unsigned int lo = w[i] & 0xFFFFu;
    int e = (int)((lo >> 7) & 0xFFu);
    cnt += (e >= 117 && e <= 137) ? 1 : 0;
  }
  return cnt < 32;
}

__device__ __forceinline__ short8 ld8(const void* P, size_t off, int isf32) {
  if (isf32) {
    const float* q = (const float*)P + off;
    float4 x = *(const float4*)q;
    float4 y = *(const float4*)(q + 4);
    short8 r;
    r[0] = (short)f2bf(x.x); r[1] = (short)f2bf(x.y);
    r[2] = (short)f2bf(x.z); r[3] = (short)f2bf(x.w);
    r[4] = (short)f2bf(y.x); r[5] = (short)f2bf(y.y);
    r[6] = (short)f2bf(y.z); r[7] = (short)f2bf(y.w);
    return r;
  }
  return *(const short8*)((const u16*)P + off);
}

__device__ __forceinline__ float ldscalar(const void* P, size_t idx, int isf32) {
  return isf32 ? ((const float*)P)[idx] : bf2f(((const u16*)P)[idx]);
}

// ---------------------------------------------------------------------------
// cvt7: one-shot fp32->bf16 of 3 X tensors + 4 W tensors. grid (1024, 7).
// ---------------------------------------------------------------------------
__global__ __launch_bounds__(256) void cvt7(
    const void* s0, const void* s1, const void* s2, const void* s3,
    const void* s4, const void* s5, const void* s6,
    u16* d0, u16* d1, u16* d2, u16* d3, u16* d4, u16* d5, u16* d6)
{
  const int z = blockIdx.y;
  const void* src; u16* dst; int n;
  switch (z) {
    case 0: src = s0; dst = d0; n = 4194304; break;
    case 1: src = s1; dst = d1; n = 4194304; break;
    case 2: src = s2; dst = d2; n = 4194304; break;
    case 3: src = s3; dst = d3; n = 1048576; break;
    case 4: src = s4; dst = d4; n = 1048576; break;
    case 5: src = s5; dst = d5; n = 1048576; break;
    default: src = s6; dst = d6; n = 1048576; break;
  }
  const int isf32 = probe_is_f32(src);
  for (int i = blockIdx.x * 256 + threadIdx.x; i * 4 < n; i += gridDim.x * 256) {
    if (isf32) {
      float4 x = ((const float4*)src)[i];
      short4v r;
      r[0] = (short)f2bf(x.x); r[1] = (short)f2bf(x.y);
      r[2] = (short)f2bf(x.z); r[3] = (short)f2bf(x.w);
      *(short4v*)(dst + (size_t)i * 4) = r;
    } else {
      *(short4v*)(dst + (size_t)i * 4) = ((const short4v*)src)[i];
    }
  }
}

// ---------------------------------------------------------------------------
// bf16 MFMA GEMM core v4: 128x64 tile, BK=32, dbuf LDS, counted vmcnt.
// R5 post-mortem: the v3 128x128 core at grid 768 = 3 blocks/CU was
// latency-bound (MfmaUtil 17, VALUBusy 13, HBM 14%, all pipes idle;
// ~4200 cyc/iter vs ~400 compute). Halving the tile doubles resident
// blocks to 6/CU (24 waves) -- TLP is the latency hider in this family
// (R1/R5 lesson). Per wave: acc[2][4] (rows wv*32..+31, all 64 cols).
// Staging: 3 global_load_lds per thread (A rows r0, r0+64; B row r0) ->
// vmcnt(3) waits current tile, prefetch stays in flight. LDS 24 KB.
// As = 8192 u16 (2 x 4096), Bs = 4096 u16 (2 x 2048).
// ---------------------------------------------------------------------------
__device__ __forceinline__ void gemm_core_bf16_n64(
    const u16* __restrict__ A, const u16* __restrict__ W,
    u16* As, u16* Bs, floatx4 acc[2][4], int m0, int n0, int K, int tid)
{
  const int lane = tid & 63, wv = tid >> 6;
  const int g = lane >> 4, ml = lane & 15;
  const int r0 = tid >> 2, kc = (tid & 3) << 3;
  const u16* Ag0 = A + (size_t)(m0 + r0) * K + kc;
  const u16* Ag1 = A + (size_t)(m0 + r0 + 64) * K + kc;
  const u16* Bg0 = W + (size_t)(n0 + r0) * K + kc;

#define STAGE_N64(buf_, kt_) do {                                              \
    u16* a0 = As + (buf_) * 4096 + tid * 8;                                    \
    u16* b0 = Bs + (buf_) * 2048 + tid * 8;                                    \
    __builtin_amdgcn_global_load_lds((const AS_GLOBAL unsigned int*)(Ag0 + (kt_)), \
                                     (AS_LDS unsigned int*)a0, 16, 0, 0);      \
    __builtin_amdgcn_global_load_lds((const AS_GLOBAL unsigned int*)(Ag1 + (kt_)), \
                                     (AS_LDS unsigned int*)(a0 + 2048), 16, 0, 0); \
    __builtin_amdgcn_global_load_lds((const AS_GLOBAL unsigned int*)(Bg0 + (kt_)), \
                                     (AS_LDS unsigned int*)b0, 16, 0, 0);      \
  } while (0)

  STAGE_N64(0, 0);
  int buf = 0;
#pragma unroll 2
  for (int kt = 0; kt < K; kt += 32) {
    const int nk = (kt + 32 < K) ? (kt + 32) : 0;   // dummy reload on last iter
    STAGE_N64(buf ^ 1, nk);
    // wait current tile (3 oldest), keep prefetch (3 newest) in flight
    __asm__ __volatile__("s_waitcnt vmcnt(3)\n\ts_barrier" ::: "memory");
    const u16* Ac = As + buf * 4096;
    const u16* Bc = Bs + buf * 2048;
    short8 af[2], bf[4];
#pragma unroll
    for (int i = 0; i < 2; ++i)
      af[i] = *(const short8*)(Ac + (wv * 32 + i * 16 + ml) * 32 + g * 8);
#pragma unroll
    for (int j = 0; j < 4; ++j)
      bf[j] = *(const short8*)(Bc + (j * 16 + ml) * 32 + g * 8);
#pragma unroll
    for (int i = 0; i < 2; ++i)
#pragma unroll
      for (int j = 0; j < 4; ++j)
        acc[i][j] = __builtin_amdgcn_mfma_f32_16x16x32_bf16(af[i], bf[j], acc[i][j], 0, 0, 0);
    // all waves done reading buf before it becomes next prefetch target
    __asm__ __volatile__("s_waitcnt lgkmcnt(0)\n\ts_barrier" ::: "memory");
    buf ^= 1;
  }
#undef STAGE_N64
  // drain dummy prefetch before epilogue / endpgm (LDS-dealloc hazard)
  __asm__ __volatile__("s_waitcnt vmcnt(0)" ::: "memory");
}

// R7-proven fallback core: BK=32, cvt-in-staging. (As/Bs = 4096 u16)
__device__ __forceinline__ void gemm_core_cvt(
    const void* __restrict__ A, const void* __restrict__ W, int aF32, int bF32,
    u16* As, u16* Bs, floatx4 acc[4][4], int m0, int n0, int K, int tid)
{
  const int lane = tid & 63, wv = tid >> 6;
  const int wm = wv >> 1, wn = wv & 1;
  const int g = lane >> 4, ml = lane & 15;
  const int r0 = tid >> 2, kc = (tid & 3) << 3;
  const size_t offA0 = (size_t)(m0 + r0) * K + kc;
  const size_t offA1 = (size_t)(m0 + r0 + 64) * K + kc;
  const size_t offB0 = (size_t)(n0 + r0) * K + kc;
  const size_t offB1 = (size_t)(n0 + r0 + 64) * K + kc;
  u16* Al0 = As + tid * 8;  u16* Al1 = As + (tid + 256) * 8;
  u16* Bl0 = Bs + tid * 8;  u16* Bl1 = Bs + (tid + 256) * 8;
  for (int kt = 0; kt < K; kt += 32) {
    short8 a0 = ld8(A, offA0 + kt, aF32);
    short8 a1 = ld8(A, offA1 + kt, aF32);
    short8 b0 = ld8(W, offB0 + kt, bF32);
    short8 b1 = ld8(W, offB1 + kt, bF32);
    *(short8*)Al0 = a0;  *(short8*)Al1 = a1;
    *(short8*)Bl0 = b0;  *(short8*)Bl1 = b1;
    __syncthreads();
    short8 af[4], bf[4];
#pragma unroll
    for (int i = 0; i < 4; ++i)
      af[i] = *(const short8*)(As + (wm * 64 + i * 16 + ml) * 32 + g * 8);
#pragma unroll
    for (int j = 0; j < 4; ++j)
      bf[j] = *(const short8*)(Bs + (wn * 64 + j * 16 + ml) * 32 + g * 8);
#pragma unroll
    for (int i = 0; i < 4; ++i)
#pragma unroll
      for (int j = 0; j < 4; ++j)
        acc[i][j] = __builtin_amdgcn_mfma_f32_16x16x32_bf16(af[i], bf[j], acc[i][j], 0, 0, 0);
    __syncthreads();
  }
}

// ---------------------------------------------------------------------------
// QKV epilogue (128x64 tile, acc[2][4]): z=0 (Q) scaled by QSCALE into
// [B,H,S,D]; z=1 (K) [B,H,S,D]; z=2 (V) TRANSPOSED into [B,H,D,S].
// gm = m0 + wv*32 + i*16 + g*4 + r ; gn = n0 + j*16 + ml.
// ---------------------------------------------------------------------------
__device__ __forceinline__ void qkv_epilogue64(
    floatx4 acc[2][4], const void* Bi, int cF32, u16* O, int m0, int n0,
    int tid, int z)
{
  const int lane = tid & 63, wv = tid >> 6;
  const int g = lane >> 4, ml = lane & 15;
  const float sc = (z == 0) ? QSCALE : 1.0f;
#pragma unroll
  for (int j = 0; j < 4; ++j) {
    int gn = n0 + j * 16 + ml;
    float bvv = ldscalar(Bi, (size_t)gn, cF32);
    int h = gn >> 6, d = gn & 63;
    if (z == 2) {
#pragma unroll
      for (int i = 0; i < 2; ++i) {
        int gm0 = m0 + wv * 32 + i * 16 + g * 4;
        int b = gm0 >> 11, s0 = gm0 & 2047;
        short4v pk;
#pragma unroll
        for (int r = 0; r < 4; ++r) pk[r] = (short)f2bf_fast(acc[i][j][r] + bvv);
        *(short4v*)(O + ((((size_t)b * 16 + h) * 64 + d) * 2048 + s0)) = pk;
      }
    } else {
#pragma unroll
      for (int i = 0; i < 2; ++i)
#pragma unroll
        for (int r = 0; r < 4; ++r) {
          int gm = m0 + wv * 32 + i * 16 + g * 4 + r;
          int b = gm >> 11, s = gm & 2047;
          O[(((size_t)b * 16 + h) * 2048 + s) * 64 + d] =
              f2bf_fast((acc[i][j][r] + bvv) * sc);
        }
    }
  }
}

// Old 128x128 epilogue kept for the cvt fallback path.
__device__ __forceinline__ void qkv_epilogue(
    floatx4 acc[4][4], const void* Bi, int cF32, u16* O, int m0, int n0,
    int tid, int z)
{
  const int lane = tid & 63, wv = tid >> 6;
  const int wm = wv >> 1, wn = wv & 1, g = lane >> 4, ml = lane & 15;
  const float sc = (z == 0) ? QSCALE : 1.0f;
#pragma unroll
  for (int j = 0; j < 4; ++j) {
    int gn = n0 + wn * 64 + j * 16 + ml;
    float bvv = ldscalar(Bi, (size_t)gn, cF32);
    int h = gn >> 6, d = gn & 63;
    if (z == 2) {
#pragma unroll
      for (int i = 0; i < 4; ++i) {
        int gm0 = m0 + wm * 64 + i * 16 + g * 4;
        int b = gm0 >> 11, s0 = gm0 & 2047;
        short4v pk;
#pragma unroll
        for (int r = 0; r < 4; ++r) pk[r] = (short)f2bf_fast(acc[i][j][r] + bvv);
        *(short4v*)(O + ((((size_t)b * 16 + h) * 64 + d) * 2048 + s0)) = pk;
      }
    } else {
#pragma unroll
      for (int i = 0; i < 4; ++i)
#pragma unroll
        for (int r = 0; r < 4; ++r) {
          int gm = m0 + wm * 64 + i * 16 + g * 4 + r;
          int b = gm >> 11, s = gm & 2047;
          O[(((size_t)b * 16 + h) * 2048 + s) * 64 + d] =
              f2bf_fast((acc[i][j][r] + bvv) * sc);
        }
    }
  }
}

// grid (32 m-tiles, 16 n-tiles, 3) = 1536 blocks -> 6 blocks/CU.
// linear id % 8 == x % 8 -> each XCD keeps a fixed quarter of X's rows hot;
// W (2MB) is L2-resident after first pass.
__global__ __launch_bounds__(256, 6) void qkv_gemm_bf16(
    const u16* __restrict__ Xq, const u16* __restrict__ Xk, const u16* __restrict__ Xv,
    const u16* __restrict__ Wq, const u16* __restrict__ Wk, const u16* __restrict__ Wv,
    const void* __restrict__ Bq, const void* __restrict__ Bk, const void* __restrict__ Bv,
    u16* __restrict__ Oq, u16* __restrict__ Ok, u16* __restrict__ Ov)
{
  __align__(16) __shared__ u16 As[8192];
  __align__(16) __shared__ u16 Bs[4096];
  const int z = blockIdx.z;
  const u16* X = (z == 0) ? Xq : (z == 1) ? Xk : Xv;
  const u16* W = (z == 0) ? Wq : (z == 1) ? Wk : Wv;
  const void* Bi = (z == 0) ? Bq : (z == 1) ? Bk : Bv;
  u16* O = (z == 0) ? Oq : (z == 1) ? Ok : Ov;
  const int tid = threadIdx.x;
  const int m0 = blockIdx.x * 128, n0 = blockIdx.y * 64;
  floatx4 acc[2][4] = {};
  gemm_core_bf16_n64(X, W, As, Bs, acc, m0, n0, 1024, tid);
  const int cF32 = probe_is_f32(Bi);   // after core: no stray vmem in loop
  qkv_epilogue64(acc, Bi, cF32, O, m0, n0, tid, z);
}

__global__ __launch_bounds__(256) void qkv_gemm_cvt(
    const void* __restrict__ Xq, const void* __restrict__ Xk, const void* __restrict__ Xv,
    const void* __restrict__ Wq, const void* __restrict__ Wk, const void* __restrict__ Wv,
    const void* __restrict__ Bq, const void* __restrict__ Bk, const void* __restrict__ Bv,
    u16* __restrict__ Oq, u16* __restrict__ Ok, u16* __restrict__ Ov)
{
  __align__(16) __shared__ u16 As[4096];
  __align__(16) __shared__ u16 Bs[4096];
  const int z = blockIdx.z;
  const void* X  = (z == 0) ? Xq : (z == 1) ? Xk : Xv;
  const void* W  = (z == 0) ? Wq : (z == 1) ? Wk : Wv;
  const void* Bi = (z == 0) ? Bq : (z == 1) ? Bk : Bv;
  u16* O = (z == 0) ? Oq : (z == 1) ? Ok : Ov;
  const int aF32 = probe_is_f32(X);
  const int bF32 = probe_is_f32(W);
  const int cF32 = probe_is_f32(Bi);
  const int tid = threadIdx.x;
  const int m0 = blockIdx.y * 128, n0 = blockIdx.x * 128;
  floatx4 acc[4][4] = {};
  gemm_core_cvt(X, W, aF32, bF32, As, Bs, acc, m0, n0, 1024, tid);
  qkv_epilogue(acc, Bi, cF32, O, m0, n0, tid, z);
}

// ---------------------------------------------------------------------------
// Output projection: 128x64 tiles, grid (32, 16) = 512 blocks (2/CU, up from
// 1/CU at 128x128). fp32 store to d_out.
// ---------------------------------------------------------------------------
__global__ __launch_bounds__(256, 6) void out_gemm_bf16(
    const u16* __restrict__ X, const u16* __restrict__ W,
    const void* __restrict__ Bi, float* __restrict__ O)
{
  __align__(16) __shared__ u16 As[8192];
  __align__(16) __shared__ u16 Bs[4096];
  const int tid = threadIdx.x;
  const int m0 = blockIdx.x * 128, n0 = blockIdx.y * 64;
  floatx4 acc[2][4] = {};
  gemm_core_bf16_n64(X, W, As, Bs, acc, m0, n0, 1024, tid);
  const int cF32 = probe_is_f32(Bi);
  const int lane = tid & 63, wv = tid >> 6;
  const int g = lane >> 4, ml = lane & 15;
#pragma unroll
  for (int j = 0; j < 4; ++j) {
    int gn = n0 + j * 16 + ml;
    float bvv = ldscalar(Bi, (size_t)gn, cF32);
#pragma unroll
    for (int i = 0; i < 2; ++i)
#pragma unroll
      for (int r = 0; r < 4; ++r) {
        int gm = m0 + wv * 32 + i * 16 + g * 4 + r;
        O[(size_t)gm * 1024 + gn] = acc[i][j][r] + bvv;
      }
  }
}

__global__ __launch_bounds__(256) void out_gemm_cvt(
    const u16* __restrict__ X, const void* __restrict__ W,
    const void* __restrict__ Bi, float* __restrict__ O)
{
  __align__(16) __shared__ u16 As[4096];
  __align__(16) __shared__ u16 Bs[4096];
  const int bF32 = probe_is_f32(W);
  const int cF32 = probe_is_f32(Bi);
  const int tid = threadIdx.x;
  const int m0 = blockIdx.y * 128, n0 = blockIdx.x * 128;
  floatx4 acc[4][4] = {};
  gemm_core_cvt(X, W, /*aF32=*/0, bF32, As, Bs, acc, m0, n0, 1024, tid);
  const int lane = tid & 63, wv = tid >> 6;
  const int wm = wv >> 1, wn = wv & 1, g = lane >> 4, ml = lane & 15;
#pragma unroll
  for (int j = 0; j < 4; ++j) {
    int gn = n0 + wn * 64 + j * 16 + ml;
    float bvv = ldscalar(Bi, (size_t)gn, cF32);
#pragma unroll
    for (int i = 0; i < 4; ++i)
#pragma unroll
      for (int r = 0; r < 4; ++r) {
        int gm = m0 + wm * 64 + i * 16 + g * 4 + r;
        O[(size_t)gm * 1024 + gn] = acc[i][j][r] + bvv;
      }
  }
}

// ---------------------------------------------------------------------------
// Flash attention v10 (unchanged from R5): 32x32 MFMA + subtiled LDS + T12,
// 4 waves x (q-half, kv-half) quadrants, K-dbuf counted-vmcnt pipeline,
// additive-partial kv-split combined via LDS at the end.
// ---------------------------------------------------------------------------
__global__ __launch_bounds__(256, 4) void flash_attn(
    const u16* __restrict__ Q, const u16* __restrict__ K, const u16* __restrict__ V,
    const int* __restrict__ Mask, u16* __restrict__ O)
{
  __align__(16) __shared__ u16 Ks[2][64 * 64];   // doubles as f32 exchange buf
  __align__(16) __shared__ u16 Vt[64 * 64];
  __align__(16) __shared__ int Ms[64];
  __align__(16) __shared__ float Lf[256];
  __shared__ int Wok[4];

  const int qt = blockIdx.x;
  const int bh = blockIdx.y;
  const int b = bh >> 4, h = bh & 15;
  const int tid = threadIdx.x;
  const int lane = tid & 63, wv = tid >> 6;
  const int qh = wv & 1, kh = wv >> 1;
  const int H = lane >> 5, lq = lane & 31;
  const int koff = lq * 16 + H * 8;        // lane slot offset within a subtile

  const size_t baseQ  = (((size_t)b * 16 + h) * 2048 + (size_t)qt * 64) * 64;
  const size_t baseKV = ((size_t)b * 16 + h) * 2048 * 64;  // V is [B,H,D,S]

  {
    int la = 1;
#pragma unroll
    for (int i = 0; i < 8; ++i) la &= Mask[b * 2048 + tid * 8 + i];
    int wall = __all(la != 0);
    if (lane == 0) Wok[wv] = wall;
  }

  // Q fragments (B-operand): rows q = qt*64 + qh*32 + lq, d = 16c + 8H + j
  short8 qf[4];
  {
    const u16* qb = Q + baseQ + (size_t)(qh * 32 + lq) * 64 + H * 8;
#pragma unroll
    for (int c = 0; c < 4; ++c)
      qf[c] = *(const short8*)(qb + c * 16);
  }

  // staging: 512 16B-slots over 256 threads x 2; subtile encoding in the
  // global source address, linear LDS dest (m173 pattern).
  const u16* kg[2]; const u16* vg[2];
  int lo[2];
#pragma unroll
  for (int t = 0; t < 2; ++t) {
    int s = tid + t * 256;
    int blk = s >> 8;                       // 32-row block
    int ch  = (s >> 6) & 3;                 // 16-u16 chunk
    int row = (s >> 1) & 31;
    int hh  = s & 1;
    kg[t] = K + baseKV + (size_t)(blk * 32 + row) * 64 + ch * 16 + hh * 8;
    vg[t] = V + baseKV + (size_t)(blk * 32 + row) * 2048 + ch * 16 + hh * 8;
    lo[t] = ((tid & 192) + t * 256) * 8;    // wave-uniform base (u16 units)
  }

  // prologue: K tile 0 -> Ks[0]
#pragma unroll
  for (int t = 0; t < 2; ++t)
    __builtin_amdgcn_global_load_lds((const AS_GLOBAL unsigned int*)kg[t],
                                     (AS_LDS unsigned int*)(&Ks[0][0] + lo[t]), 16, 0, 0);

  __syncthreads();
  const bool maskall = Wok[0] && Wok[1] && Wok[2] && Wok[3];

  floatx16 oacc0 = {}, oacc1 = {};
  float lp = 0.f;

  int buf = 0;
#pragma unroll 2
  for (int kv0 = 0; kv0 < 2048; kv0 += 64) {
    // V(kv0) -> Vt (single-buffered; end-of-prev-iter barrier protects it)
#pragma unroll
    for (int t = 0; t < 2; ++t)
      __builtin_amdgcn_global_load_lds((const AS_GLOBAL unsigned int*)(vg[t] + kv0),
                                       (AS_LDS unsigned int*)(Vt + lo[t]), 16, 0, 0);
    // K(kv0+64) -> Ks[buf^1] (dummy wrap to tile 0 on last iter)
    const int nxt = (kv0 + 64) & 2047;
#pragma unroll
    for (int t = 0; t < 2; ++t)
      __builtin_amdgcn_global_load_lds((const AS_GLOBAL unsigned int*)(kg[t] + (size_t)nxt * 64),
                                       (AS_LDS unsigned int*)(&Ks[buf ^ 1][0] + lo[t]), 16, 0, 0);
    if (!maskall && tid < 64) Ms[tid] = Mask[b * 2048 + kv0 + tid];
    // per-wave queue: [K(kv0) 2 | V(kv0) 2 | K(next) 2] -> vmcnt(4) waits K(kv0)
    __asm__ __volatile__("s_waitcnt vmcnt(4) lgkmcnt(0)\n\ts_barrier" ::: "memory");

    const u16* Kc = &Ks[buf][0];
    floatx16 a = {};
    __builtin_amdgcn_s_setprio(1);
#pragma unroll
    for (int c = 0; c < 4; ++c) {
      short8 kb = *(const short8*)(Kc + (kh * 4 + c) * 512 + koff);
      a = __builtin_amdgcn_mfma_f32_32x32x16_bf16(kb, qf[c], a, 0, 0, 0);
    }
    __builtin_amdgcn_s_setprio(0);

    float sv[16];
#pragma unroll
    for (int r = 0; r < 16; ++r) sv[r] = a[r];
    if (!maskall) {
#pragma unroll
      for (int r = 0; r < 16; ++r) {
        int ko = 32 * kh + (r & 3) + 8 * (r >> 2) + 4 * H;
        if (Ms[ko] == 0) sv[r] = -1.0e30f;
      }
    }
#pragma unroll
    for (int r = 0; r < 16; ++r) {
      float p = __builtin_amdgcn_exp2f(sv[r]);
      sv[r] = p;
      lp += p;
    }

    // ---- in-register P transpose (T12 @ 32x32, one kv-block) ----
    unsigned int Wd[8];
#pragma unroll
    for (int i = 0; i < 8; ++i)
      Wd[i] = cvtpk_bf16(sv[2 * i], sv[2 * i + 1]);
    short8 pa[2];
#define MAKE_PA(dst_, Wsrc_, base_) do {                                       \
    unsigned int u0 = Wsrc_[base_],       u1 = Wsrc_[(base_) + 1];             \
    unsigned int v0 = Wsrc_[(base_) + 2], v1 = Wsrc_[(base_) + 3];             \
    pl32_swap(u0, v0); pl32_swap(u1, v1);                                      \
    uint4v pw; pw[0] = u0; pw[1] = u1; pw[2] = v0; pw[3] = v1;                 \
    dst_ = __builtin_bit_cast(short8, pw);                                     \
  } while (0)
    MAKE_PA(pa[0], Wd, 0);
    MAKE_PA(pa[1], Wd, 4);
#undef MAKE_PA

    // V(kv0) landed; 2 K-prefetch stay in flight.
    __asm__ __volatile__("s_waitcnt vmcnt(2)\n\ts_barrier" ::: "memory");

    __builtin_amdgcn_s_setprio(1);
#pragma unroll
    for (int c = 0; c < 2; ++c) {
      short8 vb = *(const short8*)(Vt + (2 * kh + c) * 512 + koff);           // db=0
      oacc0 = __builtin_amdgcn_mfma_f32_32x32x16_bf16(pa[c], vb, oacc0, 0, 0, 0);
    }
#pragma unroll
    for (int c = 0; c < 2; ++c) {
      short8 vb = *(const short8*)(Vt + (4 + 2 * kh + c) * 512 + koff);      // db=1
      oacc1 = __builtin_amdgcn_mfma_f32_32x32x16_bf16(pa[c], vb, oacc1, 0, 0, 0);
    }
    __builtin_amdgcn_s_setprio(0);

    // all waves done reading Ks[buf] + Vt -> safe to overwrite next iter
    __asm__ __volatile__("s_barrier" ::: "memory");
    buf ^= 1;
  }
  // drain dummy prefetch; barrier before reusing Ks as the exchange buffer
  __asm__ __volatile__("s_waitcnt vmcnt(0)" ::: "memory");
  __syncthreads();

  // ---- cross-wave (kh) combine ----
  // l: in-wave H-combine, then exchange with partner wave (wv ^ 2)
  float lh = lp + __shfl_xor(lp, 32);
  Lf[wv * 64 + lane] = lh;
  // O partials: deposit the d-half this wave will NOT store.
  // Region per wave: 1024 floats at Xf + wv*1024; chunk layout w*256 + lane*4
  // (lane-contiguous float4s -> conflict-free).
  float* Xf = (float*)&Ks[0][0];
  {
    float* myreg = Xf + wv * 1024;
    const floatx16& dep = kh ? oacc0 : oacc1;   // kh0 deposits d-high, kh1 d-low
#pragma unroll
    for (int w = 0; w < 4; ++w) {
      float4 f4;
      f4.x = dep[4 * w + 0]; f4.y = dep[4 * w + 1];
      f4.z = dep[4 * w + 2]; f4.w = dep[4 * w + 3];
      *(float4*)(myreg + w * 256 + lane * 4) = f4;
    }
  }
  __syncthreads();
  const int pwv = wv ^ 2;
  float l = lh + Lf[pwv * 64 + lane];
  float inv = (l > 0.f) ? 1.0f / l : 0.f;
  floatx16 mine = kh ? oacc1 : oacc0;           // the d-half this wave stores
  {
    const float* prr = Xf + pwv * 1024;
#pragma unroll
    for (int w = 0; w < 4; ++w) {
      float4 f4 = *(const float4*)(prr + w * 256 + lane * 4);
      mine[4 * w + 0] += f4.x; mine[4 * w + 1] += f4.y;
      mine[4 * w + 2] += f4.z; mine[4 * w + 3] += f4.w;
    }
  }

#pragma unroll
  for (int r = 0; r < 16; ++r) {
    int qo = (r & 3) + 8 * (r >> 2) + 4 * H;
    float ivr = __shfl(inv, qo);           // inv lives at lane qo (q-col = qo)
    int q = qt * 64 + qh * 32 + qo;
    size_t orow = ((size_t)b * 2048 + q) * 1024 + (size_t)h * 64;
    O[orow + kh * 32 + lq] = f2bf_fast(mine[r] * ivr);
  }
}

// ---------------------------------------------------------------------------
extern "C" void kernel_launch(void* const* d_in, const int* in_sizes, int n_in,
                              void* d_out, int out_size, void* d_ws, size_t ws_size,
                              hipStream_t stream) {
  const void* q_in = d_in[0];
  const void* k_in = d_in[1];
  const void* v_in = d_in[2];
  const int* mask = (const int*)d_in[3];
  const void* Wq = d_in[4];  const void* bq = d_in[5];
  const void* Wk = d_in[6];  const void* bk = d_in[7];
  const void* Wv = d_in[8];  const void* bv = d_in[9];
  const void* Wo = d_in[10]; const void* bo = d_in[11];

  const size_t NTOK = (size_t)2 * 2048 * 1024;   // 4,194,304
  const size_t NW   = (size_t)1024 * 1024;       // 1,048,576

  if (ws_size >= (size_t)67108864) {
    u16* CXq = (u16*)d_ws;
    u16* CXk = CXq + NTOK;
    u16* CXv = CXk + NTOK;
    u16* CWq = CXv + NTOK;
    u16* CWk = CWq + NW;
    u16* CWv = CWk + NW;
    u16* CWo = CWv + NW;
    u16* Qp  = CWo + NW;
    u16* Kp  = Qp + NTOK;
    u16* Vp  = Kp + NTOK;   // [B,H,D,S]
    u16* Ao  = Vp + NTOK;

    cvt7<<<dim3(1024, 7), 256, 0, stream>>>(q_in, k_in, v_in, Wq, Wk, Wv, Wo,
                                            CXq, CXk, CXv, CWq, CWk, CWv, CWo);
    qkv_gemm_bf16<<<dim3(32, 16, 3), 256, 0, stream>>>(CXq, CXk, CXv,
                                                       CWq, CWk, CWv,
                                                       bq, bk, bv, Qp, Kp, Vp);
    flash_attn<<<dim3(32, 32), 256, 0, stream>>>(Qp, Kp, Vp, mask, Ao);
    out_gemm_bf16<<<dim3(32, 16), 256, 0, stream>>>(Ao, CWo, bo, (float*)d_out);
  } else {
    u16* Qp = (u16*)d_ws;
    u16* Kp = Qp + NTOK;
    u16* Vp = Kp + NTOK;    // [B,H,D,S]
    u16* Ao  = Vp + NTOK;

    qkv_gemm_cvt<<<dim3(8, 32, 3), 256, 0, stream>>>(q_in, k_in, v_in,
                                                     Wq, Wk, Wv, bq, bk, bv,
                                                     Qp, Kp, Vp);
    flash_attn<<<dim3(32, 32), 256, 0, stream>>>(Qp, Kp, Vp, mask, Ao);
    out_gemm_cvt<<<dim3(8, 32), 256, 0, stream>>>(Ao, Wo, bo, (float*)d_out);
  }
}

// Round 9
// 237.566 us; speedup vs baseline: 1.0628x; 1.0132x over previous
//
#include <hip/hip_runtime.h>
#include <stdint.h>

typedef unsigned short u16;
typedef __attribute__((ext_vector_type(8))) short short8;
typedef __attribute__((ext_vector_type(4))) short short4v;
typedef __attribute__((ext_vector_type(4))) float floatx4;
typedef __attribute__((ext_vector_type(16))) float floatx16;
typedef __attribute__((ext_vector_type(2))) unsigned int uint2v;
typedef __attribute__((ext_vector_type(4))) unsigned int uint4v;

#define AS_GLOBAL __attribute__((address_space(1)))
#define AS_LDS    __attribute__((address_space(3)))

// exp2 argument scale folded into Qp: 1/sqrt(1024) * log2(e)
#define QSCALE 0.045084220f

__device__ __forceinline__ float bf2f(u16 u) {
  union { unsigned int i; float f; } x; x.i = ((unsigned int)u) << 16; return x.f;
}
__device__ __forceinline__ u16 f2bf(float f) {          // RNE
  union { float f; unsigned int i; } x; x.f = f;
  unsigned int u = x.i;
  u += 0x7fffu + ((u >> 16) & 1u);
  return (u16)(u >> 16);
}
__device__ __forceinline__ u16 f2bf_fast(float f) {     // round-half-up, 2 ops
  union { float f; unsigned int i; } x; x.f = f;
  return (u16)((x.i + 0x8000u) >> 16);
}

// pack two f32 -> bf16x2 word (v_cvt_pk_bf16_f32: lo -> [15:0], hi -> [31:16])
__device__ __forceinline__ unsigned int cvtpk_bf16(float lo, float hi) {
  unsigned int w;
  __asm__("v_cvt_pk_bf16_f32 %0, %1, %2" : "=v"(w) : "v"(lo), "v"(hi));
  return w;
}

// paired half-swap (gfx950): a' = {a.lo, b.lo}, b' = {a.hi, b.hi}
__device__ __forceinline__ void pl32_swap(unsigned int& a, unsigned int& b) {
#if __has_builtin(__builtin_amdgcn_permlane32_swap)
  uint2v r = __builtin_amdgcn_permlane32_swap(a, b, false, false);
  a = r[0]; b = r[1];
#else
  __asm__("v_permlane32_swap_b32 %0, %1" : "+v"(a), "+v"(b));
#endif
}

// Runtime dtype probe (R4-validated).
__device__ __forceinline__ int probe_is_f32(const void* p) {
  const unsigned int* w = (const unsigned int*)p;
  int cnt = 0;
#pragma unroll
  for (int i = 0; i < 64; ++i) {
    unsigned int lo = w[i] & 0xFFFFu;
    int e = (int)((lo >> 7) & 0xFFu);
    cnt += (e >= 117 && e <= 137) ? 1 : 0;
  }
  return cnt < 32;
}

__device__ __forceinline__ short8 ld8(const void* P, size_t off, int isf32) {
  if (isf32) {
    const float* q = (const float*)P + off;
    float4 x = *(const float4*)q;
    float4 y = *(const float4*)(q + 4);
    short8 r;
    r[0] = (short)f2bf(x.x); r[1] = (short)f2bf(x.y);
    r[2] = (short)f2bf(x.z); r[3] = (short)f2bf(x.w);
    r[4] = (short)f2bf(y.x); r[5] = (short)f2bf(y.y);
    r[6] = (short)f2bf(y.z); r[7] = (short)f2bf(y.w);
    return r;
  }
  return *(const short8*)((const u16*)P + off);
}

__device__ __forceinline__ float ldscalar(const void* P, size_t idx, int isf32) {
  return isf32 ? ((const float*)P)[idx] : bf2f(((const u16*)P)[idx]);
}

// ---------------------------------------------------------------------------
// cvt7: one-shot fp32->bf16 of 3 X tensors + 4 W tensors. grid (1024, 7).
// ---------------------------------------------------------------------------
__global__ __launch_bounds__(256) void cvt7(
    const void* s0, const void* s1, const void* s2, const void* s3,
    const void* s4, const void* s5, const void* s6,
    u16* d0, u16* d1, u16* d2, u16* d3, u16* d4, u16* d5, u16* d6)
{
  const int z = blockIdx.y;
  const void* src; u16* dst; int n;
  switch (z) {
    case 0: src = s0; dst = d0; n = 4194304; break;
    case 1: src = s1; dst = d1; n = 4194304; break;
    case 2: src = s2; dst = d2; n = 4194304; break;
    case 3: src = s3; dst = d3; n = 1048576; break;
    case 4: src = s4; dst = d4; n = 1048576; break;
    case 5: src = s5; dst = d5; n = 1048576; break;
    default: src = s6; dst = d6; n = 1048576; break;
  }
  const int isf32 = probe_is_f32(src);
  for (int i = blockIdx.x * 256 + threadIdx.x; i * 4 < n; i += gridDim.x * 256) {
    if (isf32) {
      float4 x = ((const float4*)src)[i];
      short4v r;
      r[0] = (short)f2bf(x.x); r[1] = (short)f2bf(x.y);
      r[2] = (short)f2bf(x.z); r[3] = (short)f2bf(x.w);
      *(short4v*)(dst + (size_t)i * 4) = r;
    } else {
      *(short4v*)(dst + (size_t)i * 4) = ((const short4v*)src)[i];
    }
  }
}

// ---------------------------------------------------------------------------
// bf16 MFMA GEMM core v4: 128x64 tile, BK=32, dbuf LDS, counted vmcnt.
// 6 blocks/CU resident (R6: TLP is the latency hider in this family).
// As = 8192 u16 (2 x 4096), Bs = 4096 u16 (2 x 2048).
// ---------------------------------------------------------------------------
__device__ __forceinline__ void gemm_core_bf16_n64(
    const u16* __restrict__ A, const u16* __restrict__ W,
    u16* As, u16* Bs, floatx4 acc[2][4], int m0, int n0, int K, int tid)
{
  const int lane = tid & 63, wv = tid >> 6;
  const int g = lane >> 4, ml = lane & 15;
  const int r0 = tid >> 2, kc = (tid & 3) << 3;
  const u16* Ag0 = A + (size_t)(m0 + r0) * K + kc;
  const u16* Ag1 = A + (size_t)(m0 + r0 + 64) * K + kc;
  const u16* Bg0 = W + (size_t)(n0 + r0) * K + kc;

#define STAGE_N64(buf_, kt_) do {                                              \
    u16* a0 = As + (buf_) * 4096 + tid * 8;                                    \
    u16* b0 = Bs + (buf_) * 2048 + tid * 8;                                    \
    __builtin_amdgcn_global_load_lds((const AS_GLOBAL unsigned int*)(Ag0 + (kt_)), \
                                     (AS_LDS unsigned int*)a0, 16, 0, 0);      \
    __builtin_amdgcn_global_load_lds((const AS_GLOBAL unsigned int*)(Ag1 + (kt_)), \
                                     (AS_LDS unsigned int*)(a0 + 2048), 16, 0, 0); \
    __builtin_amdgcn_global_load_lds((const AS_GLOBAL unsigned int*)(Bg0 + (kt_)), \
                                     (AS_LDS unsigned int*)b0, 16, 0, 0);      \
  } while (0)

  STAGE_N64(0, 0);
  int buf = 0;
#pragma unroll 2
  for (int kt = 0; kt < K; kt += 32) {
    const int nk = (kt + 32 < K) ? (kt + 32) : 0;   // dummy reload on last iter
    STAGE_N64(buf ^ 1, nk);
    // wait current tile (3 oldest), keep prefetch (3 newest) in flight
    __asm__ __volatile__("s_waitcnt vmcnt(3)\n\ts_barrier" ::: "memory");
    const u16* Ac = As + buf * 4096;
    const u16* Bc = Bs + buf * 2048;
    short8 af[2], bf[4];
#pragma unroll
    for (int i = 0; i < 2; ++i)
      af[i] = *(const short8*)(Ac + (wv * 32 + i * 16 + ml) * 32 + g * 8);
#pragma unroll
    for (int j = 0; j < 4; ++j)
      bf[j] = *(const short8*)(Bc + (j * 16 + ml) * 32 + g * 8);
#pragma unroll
    for (int i = 0; i < 2; ++i)
#pragma unroll
      for (int j = 0; j < 4; ++j)
        acc[i][j] = __builtin_amdgcn_mfma_f32_16x16x32_bf16(af[i], bf[j], acc[i][j], 0, 0, 0);
    // all waves done reading buf before it becomes next prefetch target
    __asm__ __volatile__("s_waitcnt lgkmcnt(0)\n\ts_barrier" ::: "memory");
    buf ^= 1;
  }
#undef STAGE_N64
  // drain dummy prefetch before epilogue / endpgm (LDS-dealloc hazard)
  __asm__ __volatile__("s_waitcnt vmcnt(0)" ::: "memory");
}

// R7-proven fallback core: BK=32, cvt-in-staging. (As/Bs = 4096 u16)
__device__ __forceinline__ void gemm_core_cvt(
    const void* __restrict__ A, const void* __restrict__ W, int aF32, int bF32,
    u16* As, u16* Bs, floatx4 acc[4][4], int m0, int n0, int K, int tid)
{
  const int lane = tid & 63, wv = tid >> 6;
  const int wm = wv >> 1, wn = wv & 1;
  const int g = lane >> 4, ml = lane & 15;
  const int r0 = tid >> 2, kc = (tid & 3) << 3;
  const size_t offA0 = (size_t)(m0 + r0) * K + kc;
  const size_t offA1 = (size_t)(m0 + r0 + 64) * K + kc;
  const size_t offB0 = (size_t)(n0 + r0) * K + kc;
  const size_t offB1 = (size_t)(n0 + r0 + 64) * K + kc;
  u16* Al0 = As + tid * 8;  u16* Al1 = As + (tid + 256) * 8;
  u16* Bl0 = Bs + tid * 8;  u16* Bl1 = Bs + (tid + 256) * 8;
  for (int kt = 0; kt < K; kt += 32) {
    short8 a0 = ld8(A, offA0 + kt, aF32);
    short8 a1 = ld8(A, offA1 + kt, aF32);
    short8 b0 = ld8(W, offB0 + kt, bF32);
    short8 b1 = ld8(W, offB1 + kt, bF32);
    *(short8*)Al0 = a0;  *(short8*)Al1 = a1;
    *(short8*)Bl0 = b0;  *(short8*)Bl1 = b1;
    __syncthreads();
    short8 af[4], bf[4];
#pragma unroll
    for (int i = 0; i < 4; ++i)
      af[i] = *(const short8*)(As + (wm * 64 + i * 16 + ml) * 32 + g * 8);
#pragma unroll
    for (int j = 0; j < 4; ++j)
      bf[j] = *(const short8*)(Bs + (wn * 64 + j * 16 + ml) * 32 + g * 8);
#pragma unroll
    for (int i = 0; i < 4; ++i)
#pragma unroll
      for (int j = 0; j < 4; ++j)
        acc[i][j] = __builtin_amdgcn_mfma_f32_16x16x32_bf16(af[i], bf[j], acc[i][j], 0, 0, 0);
    __syncthreads();
  }
}

// ---------------------------------------------------------------------------
// QKV epilogue (128x64 tile, acc[2][4]): z=0 (Q) scaled by QSCALE into
// [B,H,S,D]; z=1 (K) [B,H,S,D]; z=2 (V) TRANSPOSED into [B,H,D,S].
// gm = m0 + wv*32 + i*16 + g*4 + r ; gn = n0 + j*16 + ml.
// ---------------------------------------------------------------------------
__device__ __forceinline__ void qkv_epilogue64(
    floatx4 acc[2][4], const void* Bi, int cF32, u16* O, int m0, int n0,
    int tid, int z)
{
  const int lane = tid & 63, wv = tid >> 6;
  const int g = lane >> 4, ml = lane & 15;
  const float sc = (z == 0) ? QSCALE : 1.0f;
#pragma unroll
  for (int j = 0; j < 4; ++j) {
    int gn = n0 + j * 16 + ml;
    float bvv = ldscalar(Bi, (size_t)gn, cF32);
    int h = gn >> 6, d = gn & 63;
    if (z == 2) {
#pragma unroll
      for (int i = 0; i < 2; ++i) {
        int gm0 = m0 + wv * 32 + i * 16 + g * 4;
        int b = gm0 >> 11, s0 = gm0 & 2047;
        short4v pk;
#pragma unroll
        for (int r = 0; r < 4; ++r) pk[r] = (short)f2bf_fast(acc[i][j][r] + bvv);
        *(short4v*)(O + ((((size_t)b * 16 + h) * 64 + d) * 2048 + s0)) = pk;
      }
    } else {
#pragma unroll
      for (int i = 0; i < 2; ++i)
#pragma unroll
        for (int r = 0; r < 4; ++r) {
          int gm = m0 + wv * 32 + i * 16 + g * 4 + r;
          int b = gm >> 11, s = gm & 2047;
          O[(((size_t)b * 16 + h) * 2048 + s) * 64 + d] =
              f2bf_fast((acc[i][j][r] + bvv) * sc);
        }
    }
  }
}

// Old 128x128 epilogue kept for the cvt fallback path.
__device__ __forceinline__ void qkv_epilogue(
    floatx4 acc[4][4], const void* Bi, int cF32, u16* O, int m0, int n0,
    int tid, int z)
{
  const int lane = tid & 63, wv = tid >> 6;
  const int wm = wv >> 1, wn = wv & 1, g = lane >> 4, ml = lane & 15;
  const float sc = (z == 0) ? QSCALE : 1.0f;
#pragma unroll
  for (int j = 0; j < 4; ++j) {
    int gn = n0 + wn * 64 + j * 16 + ml;
    float bvv = ldscalar(Bi, (size_t)gn, cF32);
    int h = gn >> 6, d = gn & 63;
    if (z == 2) {
#pragma unroll
      for (int i = 0; i < 4; ++i) {
        int gm0 = m0 + wm * 64 + i * 16 + g * 4;
        int b = gm0 >> 11, s0 = gm0 & 2047;
        short4v pk;
#pragma unroll
        for (int r = 0; r < 4; ++r) pk[r] = (short)f2bf_fast(acc[i][j][r] + bvv);
        *(short4v*)(O + ((((size_t)b * 16 + h) * 64 + d) * 2048 + s0)) = pk;
      }
    } else {
#pragma unroll
      for (int i = 0; i < 4; ++i)
#pragma unroll
        for (int r = 0; r < 4; ++r) {
          int gm = m0 + wm * 64 + i * 16 + g * 4 + r;
          int b = gm >> 11, s = gm & 2047;
          O[(((size_t)b * 16 + h) * 2048 + s) * 64 + d] =
              f2bf_fast((acc[i][j][r] + bvv) * sc);
        }
    }
  }
}

// grid (32 m-tiles, 16 n-tiles, 3) = 1536 blocks -> 6 blocks/CU.
__global__ __launch_bounds__(256, 6) void qkv_gemm_bf16(
    const u16* __restrict__ Xq, const u16* __restrict__ Xk, const u16* __restrict__ Xv,
    const u16* __restrict__ Wq, const u16* __restrict__ Wk, const u16* __restrict__ Wv,
    const void* __restrict__ Bq, const void* __restrict__ Bk, const void* __restrict__ Bv,
    u16* __restrict__ Oq, u16* __restrict__ Ok, u16* __restrict__ Ov)
{
  __align__(16) __shared__ u16 As[8192];
  __align__(16) __shared__ u16 Bs[4096];
  const int z = blockIdx.z;
  const u16* X = (z == 0) ? Xq : (z == 1) ? Xk : Xv;
  const u16* W = (z == 0) ? Wq : (z == 1) ? Wk : Wv;
  const void* Bi = (z == 0) ? Bq : (z == 1) ? Bk : Bv;
  u16* O = (z == 0) ? Oq : (z == 1) ? Ok : Ov;
  const int tid = threadIdx.x;
  const int m0 = blockIdx.x * 128, n0 = blockIdx.y * 64;
  floatx4 acc[2][4] = {};
  gemm_core_bf16_n64(X, W, As, Bs, acc, m0, n0, 1024, tid);
  const int cF32 = probe_is_f32(Bi);   // after core: no stray vmem in loop
  qkv_epilogue64(acc, Bi, cF32, O, m0, n0, tid, z);
}

__global__ __launch_bounds__(256) void qkv_gemm_cvt(
    const void* __restrict__ Xq, const void* __restrict__ Xk, const void* __restrict__ Xv,
    const void* __restrict__ Wq, const void* __restrict__ Wk, const void* __restrict__ Wv,
    const void* __restrict__ Bq, const void* __restrict__ Bk, const void* __restrict__ Bv,
    u16* __restrict__ Oq, u16* __restrict__ Ok, u16* __restrict__ Ov)
{
  __align__(16) __shared__ u16 As[4096];
  __align__(16) __shared__ u16 Bs[4096];
  const int z = blockIdx.z;
  const void* X  = (z == 0) ? Xq : (z == 1) ? Xk : Xv;
  const void* W  = (z == 0) ? Wq : (z == 1) ? Wk : Wv;
  const void* Bi = (z == 0) ? Bq : (z == 1) ? Bk : Bv;
  u16* O = (z == 0) ? Oq : (z == 1) ? Ok : Ov;
  const int aF32 = probe_is_f32(X);
  const int bF32 = probe_is_f32(W);
  const int cF32 = probe_is_f32(Bi);
  const int tid = threadIdx.x;
  const int m0 = blockIdx.y * 128, n0 = blockIdx.x * 128;
  floatx4 acc[4][4] = {};
  gemm_core_cvt(X, W, aF32, bF32, As, Bs, acc, m0, n0, 1024, tid);
  qkv_epilogue(acc, Bi, cF32, O, m0, n0, tid, z);
}

// ---------------------------------------------------------------------------
// Output projection: 128x64 tiles, grid (32, 16) = 512 blocks. fp32 store.
// ---------------------------------------------------------------------------
__global__ __launch_bounds__(256, 6) void out_gemm_bf16(
    const u16* __restrict__ X, const u16* __restrict__ W,
    const void* __restrict__ Bi, float* __restrict__ O)
{
  __align__(16) __shared__ u16 As[8192];
  __align__(16) __shared__ u16 Bs[4096];
  const int tid = threadIdx.x;
  const int m0 = blockIdx.x * 128, n0 = blockIdx.y * 64;
  floatx4 acc[2][4] = {};
  gemm_core_bf16_n64(X, W, As, Bs, acc, m0, n0, 1024, tid);
  const int cF32 = probe_is_f32(Bi);
  const int lane = tid & 63, wv = tid >> 6;
  const int g = lane >> 4, ml = lane & 15;
#pragma unroll
  for (int j = 0; j < 4; ++j) {
    int gn = n0 + j * 16 + ml;
    float bvv = ldscalar(Bi, (size_t)gn, cF32);
#pragma unroll
    for (int i = 0; i < 2; ++i)
#pragma unroll
      for (int r = 0; r < 4; ++r) {
        int gm = m0 + wv * 32 + i * 16 + g * 4 + r;
        O[(size_t)gm * 1024 + gn] = acc[i][j][r] + bvv;
      }
  }
}

__global__ __launch_bounds__(256) void out_gemm_cvt(
    const u16* __restrict__ X, const void* __restrict__ W,
    const void* __restrict__ Bi, float* __restrict__ O)
{
  __align__(16) __shared__ u16 As[4096];
  __align__(16) __shared__ u16 Bs[4096];
  const int bF32 = probe_is_f32(W);
  const int cF32 = probe_is_f32(Bi);
  const int tid = threadIdx.x;
  const int m0 = blockIdx.y * 128, n0 = blockIdx.x * 128;
  floatx4 acc[4][4] = {};
  gemm_core_cvt(X, W, /*aF32=*/0, bF32, As, Bs, acc, m0, n0, 1024, tid);
  const int lane = tid & 63, wv = tid >> 6;
  const int wm = wv >> 1, wn = wv & 1, g = lane >> 4, ml = lane & 15;
#pragma unroll
  for (int j = 0; j < 4; ++j) {
    int gn = n0 + wn * 64 + j * 16 + ml;
    float bvv = ldscalar(Bi, (size_t)gn, cF32);
#pragma unroll
    for (int i = 0; i < 4; ++i)
#pragma unroll
      for (int r = 0; r < 4; ++r) {
        int gm = m0 + wm * 64 + i * 16 + g * 4 + r;
        O[(size_t)gm * 1024 + gn] = acc[i][j][r] + bvv;
      }
  }
}

// ---------------------------------------------------------------------------
// Flash attention v11b: v11 (K+V both double-buffered, prefetched one full
// iteration ahead, 2 barriers/iter, no mid-loop vmcnt) with the R7 bug fixed:
// V is [B,H,D,S] so the kv index is the FASTEST dim (stride 1) -- the V
// prefetch offset is vg[t] + nxt, NOT vg[t] + nxt*64 (that stride belongs to
// K's [B,H,S,D] layout). v10 had this right; v11's refactor broke it.
// Pipeline hazards re-verified: iter-i prefetch writes buf^1 == buf_{i-1},
// ordered after the end-of-iter-(i-1) barrier which closes all reads of it;
// vmcnt retires in issue order per wave, so vmcnt(4) at iter i guarantees
// K(i),V(i) (issued iter i-1) have landed. LDS 33.3 KB -> 4 blocks/CU
// (residency unchanged vs v10; no v6-style occupancy regression).
// (R8 bench was an infra failure -- container died twice; resubmitting
// unchanged to get the measurement.)
// ---------------------------------------------------------------------------
__global__ __launch_bounds__(256, 4) void flash_attn(
    const u16* __restrict__ Q, const u16* __restrict__ K, const u16* __restrict__ V,
    const int* __restrict__ Mask, u16* __restrict__ O)
{
  __align__(16) __shared__ u16 Ks[2][64 * 64];   // doubles as f32 exchange buf
  __align__(16) __shared__ u16 Vt[2][64 * 64];
  __align__(16) __shared__ int Ms[64];
  __align__(16) __shared__ float Lf[256];
  __shared__ int Wok[4];

  const int qt = blockIdx.x;
  const int bh = blockIdx.y;
  const int b = bh >> 4, h = bh & 15;
  const int tid = threadIdx.x;
  const int lane = tid & 63, wv = tid >> 6;
  const int qh = wv & 1, kh = wv >> 1;
  const int H = lane >> 5, lq = lane & 31;
  const int koff = lq * 16 + H * 8;        // lane slot offset within a subtile

  const size_t baseQ  = (((size_t)b * 16 + h) * 2048 + (size_t)qt * 64) * 64;
  const size_t baseKV = ((size_t)b * 16 + h) * 2048 * 64;  // V is [B,H,D,S]

  {
    int la = 1;
#pragma unroll
    for (int i = 0; i < 8; ++i) la &= Mask[b * 2048 + tid * 8 + i];
    int wall = __all(la != 0);
    if (lane == 0) Wok[wv] = wall;
  }

  // Q fragments (B-operand): rows q = qt*64 + qh*32 + lq, d = 16c + 8H + j
  short8 qf[4];
  {
    const u16* qb = Q + baseQ + (size_t)(qh * 32 + lq) * 64 + H * 8;
#pragma unroll
    for (int c = 0; c < 4; ++c)
      qf[c] = *(const short8*)(qb + c * 16);
  }

  // staging: 512 16B-slots over 256 threads x 2; subtile encoding in the
  // global source address, linear LDS dest (m173 pattern).
  const u16* kg[2]; const u16* vg[2];
  int lo[2];
#pragma unroll
  for (int t = 0; t < 2; ++t) {
    int s = tid + t * 256;
    int blk = s >> 8;                       // 32-row block
    int ch  = (s >> 6) & 3;                 // 16-u16 chunk
    int row = (s >> 1) & 31;
    int hh  = s & 1;
    kg[t] = K + baseKV + (size_t)(blk * 32 + row) * 64 + ch * 16 + hh * 8;
    vg[t] = V + baseKV + (size_t)(blk * 32 + row) * 2048 + ch * 16 + hh * 8;
    lo[t] = ((tid & 192) + t * 256) * 8;    // wave-uniform base (u16 units)
  }

  // prologue: K(0) -> Ks[0], V(0) -> Vt[0]
#pragma unroll
  for (int t = 0; t < 2; ++t) {
    __builtin_amdgcn_global_load_lds((const AS_GLOBAL unsigned int*)kg[t],
                                     (AS_LDS unsigned int*)(&Ks[0][0] + lo[t]), 16, 0, 0);
    __builtin_amdgcn_global_load_lds((const AS_GLOBAL unsigned int*)vg[t],
                                     (AS_LDS unsigned int*)(&Vt[0][0] + lo[t]), 16, 0, 0);
  }

  __syncthreads();
  const bool maskall = Wok[0] && Wok[1] && Wok[2] && Wok[3];

  floatx16 oacc0 = {}, oacc1 = {};
  float lp = 0.f;

  int buf = 0;
#pragma unroll 2
  for (int kv0 = 0; kv0 < 2048; kv0 += 64) {
    // prefetch NEXT tile (K and V) into buf^1 (dummy wrap on last iter).
    // K rows stride 64 (S-major); V kv index is stride-1 (S fastest).
    const int nxt = (kv0 + 64) & 2047;
#pragma unroll
    for (int t = 0; t < 2; ++t) {
      __builtin_amdgcn_global_load_lds((const AS_GLOBAL unsigned int*)(vg[t] + nxt),
                                       (AS_LDS unsigned int*)(&Vt[buf ^ 1][0] + lo[t]), 16, 0, 0);
      __builtin_amdgcn_global_load_lds((const AS_GLOBAL unsigned int*)(kg[t] + (size_t)nxt * 64),
                                       (AS_LDS unsigned int*)(&Ks[buf ^ 1][0] + lo[t]), 16, 0, 0);
    }
    if (!maskall && tid < 64) Ms[tid] = Mask[b * 2048 + kv0 + tid];
    // wait current tile (4 oldest: K(i),V(i) issued last iter); keep 4 new
    // prefetch ops in flight. lgkmcnt(0) covers the Ms ds_write (cold path).
    __asm__ __volatile__("s_waitcnt vmcnt(4) lgkmcnt(0)\n\ts_barrier" ::: "memory");

    const u16* Kc = &Ks[buf][0];
    floatx16 a = {};
    __builtin_amdgcn_s_setprio(1);
#pragma unroll
    for (int c = 0; c < 4; ++c) {
      short8 kb = *(const short8*)(Kc + (kh * 4 + c) * 512 + koff);
      a = __builtin_amdgcn_mfma_f32_32x32x16_bf16(kb, qf[c], a, 0, 0, 0);
    }
    __builtin_amdgcn_s_setprio(0);

    float sv[16];
#pragma unroll
    for (int r = 0; r < 16; ++r) sv[r] = a[r];
    if (!maskall) {
#pragma unroll
      for (int r = 0; r < 16; ++r) {
        int ko = 32 * kh + (r & 3) + 8 * (r >> 2) + 4 * H;
        if (Ms[ko] == 0) sv[r] = -1.0e30f;
      }
    }
#pragma unroll
    for (int r = 0; r < 16; ++r) {
      float p = __builtin_amdgcn_exp2f(sv[r]);
      sv[r] = p;
      lp += p;
    }

    // ---- in-register P transpose (T12 @ 32x32, one kv-block) ----
    unsigned int Wd[8];
#pragma unroll
    for (int i = 0; i < 8; ++i)
      Wd[i] = cvtpk_bf16(sv[2 * i], sv[2 * i + 1]);
    short8 pa[2];
#define MAKE_PA(dst_, Wsrc_, base_) do {                                       \
    unsigned int u0 = Wsrc_[base_],       u1 = Wsrc_[(base_) + 1];             \
    unsigned int v0 = Wsrc_[(base_) + 2], v1 = Wsrc_[(base_) + 3];             \
    pl32_swap(u0, v0); pl32_swap(u1, v1);                                      \
    uint4v pw; pw[0] = u0; pw[1] = u1; pw[2] = v0; pw[3] = v1;                 \
    dst_ = __builtin_bit_cast(short8, pw);                                     \
  } while (0)
    MAKE_PA(pa[0], Wd, 0);
    MAKE_PA(pa[1], Wd, 4);
#undef MAKE_PA

    // PV directly: V(i) landed (covered by the vmcnt(4) above).
    const u16* Vc = &Vt[buf][0];
    __builtin_amdgcn_s_setprio(1);
#pragma unroll
    for (int c = 0; c < 2; ++c) {
      short8 vb = *(const short8*)(Vc + (2 * kh + c) * 512 + koff);           // db=0
      oacc0 = __builtin_amdgcn_mfma_f32_32x32x16_bf16(pa[c], vb, oacc0, 0, 0, 0);
    }
#pragma unroll
    for (int c = 0; c < 2; ++c) {
      short8 vb = *(const short8*)(Vc + (4 + 2 * kh + c) * 512 + koff);      // db=1
      oacc1 = __builtin_amdgcn_mfma_f32_32x32x16_bf16(pa[c], vb, oacc1, 0, 0, 0);
    }
    __builtin_amdgcn_s_setprio(0);

    // all waves done reading Ks[buf] + Vt[buf] -> next iter may prefetch
    // into buf (which becomes its buf^1)
    __asm__ __volatile__("s_barrier" ::: "memory");
    buf ^= 1;
  }
  // drain dummy prefetch; barrier before reusing Ks as the exchange buffer
  __asm__ __volatile__("s_waitcnt vmcnt(0)" ::: "memory");
  __syncthreads();

  // ---- cross-wave (kh) combine ----
  // l: in-wave H-combine, then exchange with partner wave (wv ^ 2)
  float lh = lp + __shfl_xor(lp, 32);
  Lf[wv * 64 + lane] = lh;
  // O partials: deposit the d-half this wave will NOT store.
  // Region per wave: 1024 floats at Xf + wv*1024; chunk layout w*256 + lane*4
  // (lane-contiguous float4s -> conflict-free).
  float* Xf = (float*)&Ks[0][0];
  {
    float* myreg = Xf + wv * 1024;
    const floatx16& dep = kh ? oacc0 : oacc1;   // kh0 deposits d-high, kh1 d-low
#pragma unroll
    for (int w = 0; w < 4; ++w) {
      float4 f4;
      f4.x = dep[4 * w + 0]; f4.y = dep[4 * w + 1];
      f4.z = dep[4 * w + 2]; f4.w = dep[4 * w + 3];
      *(float4*)(myreg + w * 256 + lane * 4) = f4;
    }
  }
  __syncthreads();
  const int pwv = wv ^ 2;
  float l = lh + Lf[pwv * 64 + lane];
  float inv = (l > 0.f) ? 1.0f / l : 0.f;
  floatx16 mine = kh ? oacc1 : oacc0;           // the d-half this wave stores
  {
    const float* prr = Xf + pwv * 1024;
#pragma unroll
    for (int w = 0; w < 4; ++w) {
      float4 f4 = *(const float4*)(prr + w * 256 + lane * 4);
      mine[4 * w + 0] += f4.x; mine[4 * w + 1] += f4.y;
      mine[4 * w + 2] += f4.z; mine[4 * w + 3] += f4.w;
    }
  }

#pragma unroll
  for (int r = 0; r < 16; ++r) {
    int qo = (r & 3) + 8 * (r >> 2) + 4 * H;
    float ivr = __shfl(inv, qo);           // inv lives at lane qo (q-col = qo)
    int q = qt * 64 + qh * 32 + qo;
    size_t orow = ((size_t)b * 2048 + q) * 1024 + (size_t)h * 64;
    O[orow + kh * 32 + lq] = f2bf_fast(mine[r] * ivr);
  }
}

// ---------------------------------------------------------------------------
extern "C" void kernel_launch(void* const* d_in, const int* in_sizes, int n_in,
                              void* d_out, int out_size, void* d_ws, size_t ws_size,
                              hipStream_t stream) {
  const void* q_in = d_in[0];
  const void* k_in = d_in[1];
  const void* v_in = d_in[2];
  const int* mask = (const int*)d_in[3];
  const void* Wq = d_in[4];  const void* bq = d_in[5];
  const void* Wk = d_in[6];  const void* bk = d_in[7];
  const void* Wv = d_in[8];  const void* bv = d_in[9];
  const void* Wo = d_in[10]; const void* bo = d_in[11];

  const size_t NTOK = (size_t)2 * 2048 * 1024;   // 4,194,304
  const size_t NW   = (size_t)1024 * 1024;       // 1,048,576

  if (ws_size >= (size_t)67108864) {
    u16* CXq = (u16*)d_ws;
    u16* CXk = CXq + NTOK;
    u16* CXv = CXk + NTOK;
    u16* CWq = CXv + NTOK;
    u16* CWk = CWq + NW;
    u16* CWv = CWk + NW;
    u16* CWo = CWv + NW;
    u16* Qp  = CWo + NW;
    u16* Kp  = Qp + NTOK;
    u16* Vp  = Kp + NTOK;   // [B,H,D,S]
    u16* Ao  = Vp + NTOK;

    cvt7<<<dim3(1024, 7), 256, 0, stream>>>(q_in, k_in, v_in, Wq, Wk, Wv, Wo,
                                            CXq, CXk, CXv, CWq, CWk, CWv, CWo);
    qkv_gemm_bf16<<<dim3(32, 16, 3), 256, 0, stream>>>(CXq, CXk, CXv,
                                                       CWq, CWk, CWv,
                                                       bq, bk, bv, Qp, Kp, Vp);
    flash_attn<<<dim3(32, 32), 256, 0, stream>>>(Qp, Kp, Vp, mask, Ao);
    out_gemm_bf16<<<dim3(32, 16), 256, 0, stream>>>(Ao, CWo, bo, (float*)d_out);
  } else {
    u16* Qp = (u16*)d_ws;
    u16* Kp = Qp + NTOK;
    u16* Vp = Kp + NTOK;    // [B,H,D,S]
    u16* Ao  = Vp + NTOK;

    qkv_gemm_cvt<<<dim3(8, 32, 3), 256, 0, stream>>>(q_in, k_in, v_in,
                                                     Wq, Wk, Wv, bq, bk, bv,
                                                     Qp, Kp, Vp);
    flash_attn<<<dim3(32, 32), 256, 0, stream>>>(Qp, Kp, Vp, mask, Ao);
    out_gemm_cvt<<<dim3(8, 32), 256, 0, stream>>>(Ao, Wo, bo, (float*)d_out);
  }
}

// Round 10
// 235.191 us; speedup vs baseline: 1.0735x; 1.0101x over previous
//
#include <hip/hip_runtime.h>
#include <stdint.h>

typedef unsigned short u16;
typedef __attribute__((ext_vector_type(8))) short short8;
typedef __attribute__((ext_vector_type(4))) short short4v;
typedef __attribute__((ext_vector_type(4))) float floatx4;
typedef __attribute__((ext_vector_type(16))) float floatx16;
typedef __attribute__((ext_vector_type(2))) unsigned int uint2v;
typedef __attribute__((ext_vector_type(4))) unsigned int uint4v;

#define AS_GLOBAL __attribute__((address_space(1)))
#define AS_LDS    __attribute__((address_space(3)))

// exp2 argument scale folded into Qp: 1/sqrt(1024) * log2(e)
#define QSCALE 0.045084220f

__device__ __forceinline__ float bf2f(u16 u) {
  union { unsigned int i; float f; } x; x.i = ((unsigned int)u) << 16; return x.f;
}
__device__ __forceinline__ u16 f2bf(float f) {          // RNE
  union { float f; unsigned int i; } x; x.f = f;
  unsigned int u = x.i;
  u += 0x7fffu + ((u >> 16) & 1u);
  return (u16)(u >> 16);
}
__device__ __forceinline__ u16 f2bf_fast(float f) {     // round-half-up, 2 ops
  union { float f; unsigned int i; } x; x.f = f;
  return (u16)((x.i + 0x8000u) >> 16);
}

// pack two f32 -> bf16x2 word (v_cvt_pk_bf16_f32: lo -> [15:0], hi -> [31:16])
__device__ __forceinline__ unsigned int cvtpk_bf16(float lo, float hi) {
  unsigned int w;
  __asm__("v_cvt_pk_bf16_f32 %0, %1, %2" : "=v"(w) : "v"(lo), "v"(hi));
  return w;
}

// paired half-swap (gfx950): a' = {a.lo, b.lo}, b' = {a.hi, b.hi}
__device__ __forceinline__ void pl32_swap(unsigned int& a, unsigned int& b) {
#if __has_builtin(__builtin_amdgcn_permlane32_swap)
  uint2v r = __builtin_amdgcn_permlane32_swap(a, b, false, false);
  a = r[0]; b = r[1];
#else
  __asm__("v_permlane32_swap_b32 %0, %1" : "+v"(a), "+v"(b));
#endif
}

// Runtime dtype probe (R4-validated).
__device__ __forceinline__ int probe_is_f32(const void* p) {
  const unsigned int* w = (const unsigned int*)p;
  int cnt = 0;
#pragma unroll
  for (int i = 0; i < 64; ++i) {
    unsigned int lo = w[i] & 0xFFFFu;
    int e = (int)((lo >> 7) & 0xFFu);
    cnt += (e >= 117 && e <= 137) ? 1 : 0;
  }
  return cnt < 32;
}

__device__ __forceinline__ short8 ld8(const void* P, size_t off, int isf32) {
  if (isf32) {
    const float* q = (const float*)P + off;
    float4 x = *(const float4*)q;
    float4 y = *(const float4*)(q + 4);
    short8 r;
    r[0] = (short)f2bf(x.x); r[1] = (short)f2bf(x.y);
    r[2] = (short)f2bf(x.z); r[3] = (short)f2bf(x.w);
    r[4] = (short)f2bf(y.x); r[5] = (short)f2bf(y.y);
    r[6] = (short)f2bf(y.z); r[7] = (short)f2bf(y.w);
    return r;
  }
  return *(const short8*)((const u16*)P + off);
}

__device__ __forceinline__ float ldscalar(const void* P, size_t idx, int isf32) {
  return isf32 ? ((const float*)P)[idx] : bf2f(((const u16*)P)[idx]);
}

// ---------------------------------------------------------------------------
// cvt7: one-shot fp32->bf16 of 3 X tensors + 4 W tensors. grid (1024, 7).
// ---------------------------------------------------------------------------
__global__ __launch_bounds__(256) void cvt7(
    const void* s0, const void* s1, const void* s2, const void* s3,
    const void* s4, const void* s5, const void* s6,
    u16* d0, u16* d1, u16* d2, u16* d3, u16* d4, u16* d5, u16* d6)
{
  const int z = blockIdx.y;
  const void* src; u16* dst; int n;
  switch (z) {
    case 0: src = s0; dst = d0; n = 4194304; break;
    case 1: src = s1; dst = d1; n = 4194304; break;
    case 2: src = s2; dst = d2; n = 4194304; break;
    case 3: src = s3; dst = d3; n = 1048576; break;
    case 4: src = s4; dst = d4; n = 1048576; break;
    case 5: src = s5; dst = d5; n = 1048576; break;
    default: src = s6; dst = d6; n = 1048576; break;
  }
  const int isf32 = probe_is_f32(src);
  for (int i = blockIdx.x * 256 + threadIdx.x; i * 4 < n; i += gridDim.x * 256) {
    if (isf32) {
      float4 x = ((const float4*)src)[i];
      short4v r;
      r[0] = (short)f2bf(x.x); r[1] = (short)f2bf(x.y);
      r[2] = (short)f2bf(x.z); r[3] = (short)f2bf(x.w);
      *(short4v*)(dst + (size_t)i * 4) = r;
    } else {
      *(short4v*)(dst + (size_t)i * 4) = ((const short4v*)src)[i];
    }
  }
}

// ---------------------------------------------------------------------------
// bf16 MFMA GEMM core v4: 128x64 tile, BK=32, dbuf LDS, counted vmcnt.
// 6 blocks/CU resident (R6: TLP is the latency hider in this family).
// As = 8192 u16 (2 x 4096), Bs = 4096 u16 (2 x 2048).
// ---------------------------------------------------------------------------
__device__ __forceinline__ void gemm_core_bf16_n64(
    const u16* __restrict__ A, const u16* __restrict__ W,
    u16* As, u16* Bs, floatx4 acc[2][4], int m0, int n0, int K, int tid)
{
  const int lane = tid & 63, wv = tid >> 6;
  const int g = lane >> 4, ml = lane & 15;
  const int r0 = tid >> 2, kc = (tid & 3) << 3;
  const u16* Ag0 = A + (size_t)(m0 + r0) * K + kc;
  const u16* Ag1 = A + (size_t)(m0 + r0 + 64) * K + kc;
  const u16* Bg0 = W + (size_t)(n0 + r0) * K + kc;

#define STAGE_N64(buf_, kt_) do {                                              \
    u16* a0 = As + (buf_) * 4096 + tid * 8;                                    \
    u16* b0 = Bs + (buf_) * 2048 + tid * 8;                                    \
    __builtin_amdgcn_global_load_lds((const AS_GLOBAL unsigned int*)(Ag0 + (kt_)), \
                                     (AS_LDS unsigned int*)a0, 16, 0, 0);      \
    __builtin_amdgcn_global_load_lds((const AS_GLOBAL unsigned int*)(Ag1 + (kt_)), \
                                     (AS_LDS unsigned int*)(a0 + 2048), 16, 0, 0); \
    __builtin_amdgcn_global_load_lds((const AS_GLOBAL unsigned int*)(Bg0 + (kt_)), \
                                     (AS_LDS unsigned int*)b0, 16, 0, 0);      \
  } while (0)

  STAGE_N64(0, 0);
  int buf = 0;
#pragma unroll 2
  for (int kt = 0; kt < K; kt += 32) {
    const int nk = (kt + 32 < K) ? (kt + 32) : 0;   // dummy reload on last iter
    STAGE_N64(buf ^ 1, nk);
    // wait current tile (3 oldest), keep prefetch (3 newest) in flight
    __asm__ __volatile__("s_waitcnt vmcnt(3)\n\ts_barrier" ::: "memory");
    const u16* Ac = As + buf * 4096;
    const u16* Bc = Bs + buf * 2048;
    short8 af[2], bf[4];
#pragma unroll
    for (int i = 0; i < 2; ++i)
      af[i] = *(const short8*)(Ac + (wv * 32 + i * 16 + ml) * 32 + g * 8);
#pragma unroll
    for (int j = 0; j < 4; ++j)
      bf[j] = *(const short8*)(Bc + (j * 16 + ml) * 32 + g * 8);
#pragma unroll
    for (int i = 0; i < 2; ++i)
#pragma unroll
      for (int j = 0; j < 4; ++j)
        acc[i][j] = __builtin_amdgcn_mfma_f32_16x16x32_bf16(af[i], bf[j], acc[i][j], 0, 0, 0);
    // all waves done reading buf before it becomes next prefetch target
    __asm__ __volatile__("s_waitcnt lgkmcnt(0)\n\ts_barrier" ::: "memory");
    buf ^= 1;
  }
#undef STAGE_N64
  // drain dummy prefetch before epilogue / endpgm (LDS-dealloc hazard)
  __asm__ __volatile__("s_waitcnt vmcnt(0)" ::: "memory");
}

// R7-proven fallback core: BK=32, cvt-in-staging. (As/Bs = 4096 u16)
__device__ __forceinline__ void gemm_core_cvt(
    const void* __restrict__ A, const void* __restrict__ W, int aF32, int bF32,
    u16* As, u16* Bs, floatx4 acc[4][4], int m0, int n0, int K, int tid)
{
  const int lane = tid & 63, wv = tid >> 6;
  const int wm = wv >> 1, wn = wv & 1;
  const int g = lane >> 4, ml = lane & 15;
  const int r0 = tid >> 2, kc = (tid & 3) << 3;
  const size_t offA0 = (size_t)(m0 + r0) * K + kc;
  const size_t offA1 = (size_t)(m0 + r0 + 64) * K + kc;
  const size_t offB0 = (size_t)(n0 + r0) * K + kc;
  const size_t offB1 = (size_t)(n0 + r0 + 64) * K + kc;
  u16* Al0 = As + tid * 8;  u16* Al1 = As + (tid + 256) * 8;
  u16* Bl0 = Bs + tid * 8;  u16* Bl1 = Bs + (tid + 256) * 8;
  for (int kt = 0; kt < K; kt += 32) {
    short8 a0 = ld8(A, offA0 + kt, aF32);
    short8 a1 = ld8(A, offA1 + kt, aF32);
    short8 b0 = ld8(W, offB0 + kt, bF32);
    short8 b1 = ld8(W, offB1 + kt, bF32);
    *(short8*)Al0 = a0;  *(short8*)Al1 = a1;
    *(short8*)Bl0 = b0;  *(short8*)Bl1 = b1;
    __syncthreads();
    short8 af[4], bf[4];
#pragma unroll
    for (int i = 0; i < 4; ++i)
      af[i] = *(const short8*)(As + (wm * 64 + i * 16 + ml) * 32 + g * 8);
#pragma unroll
    for (int j = 0; j < 4; ++j)
      bf[j] = *(const short8*)(Bs + (wn * 64 + j * 16 + ml) * 32 + g * 8);
#pragma unroll
    for (int i = 0; i < 4; ++i)
#pragma unroll
      for (int j = 0; j < 4; ++j)
        acc[i][j] = __builtin_amdgcn_mfma_f32_16x16x32_bf16(af[i], bf[j], acc[i][j], 0, 0, 0);
    __syncthreads();
  }
}

// ---------------------------------------------------------------------------
// QKV epilogue (128x64 tile, acc[2][4]): z=0 (Q) scaled by QSCALE into
// [B,H,S,D]; z=1 (K) [B,H,S,D]; z=2 (V) TRANSPOSED into [B,H,D,S].
// gm = m0 + wv*32 + i*16 + g*4 + r ; gn = n0 + j*16 + ml.
// ---------------------------------------------------------------------------
__device__ __forceinline__ void qkv_epilogue64(
    floatx4 acc[2][4], const void* Bi, int cF32, u16* O, int m0, int n0,
    int tid, int z)
{
  const int lane = tid & 63, wv = tid >> 6;
  const int g = lane >> 4, ml = lane & 15;
  const float sc = (z == 0) ? QSCALE : 1.0f;
#pragma unroll
  for (int j = 0; j < 4; ++j) {
    int gn = n0 + j * 16 + ml;
    float bvv = ldscalar(Bi, (size_t)gn, cF32);
    int h = gn >> 6, d = gn & 63;
    if (z == 2) {
#pragma unroll
      for (int i = 0; i < 2; ++i) {
        int gm0 = m0 + wv * 32 + i * 16 + g * 4;
        int b = gm0 >> 11, s0 = gm0 & 2047;
        short4v pk;
#pragma unroll
        for (int r = 0; r < 4; ++r) pk[r] = (short)f2bf_fast(acc[i][j][r] + bvv);
        *(short4v*)(O + ((((size_t)b * 16 + h) * 64 + d) * 2048 + s0)) = pk;
      }
    } else {
#pragma unroll
      for (int i = 0; i < 2; ++i)
#pragma unroll
        for (int r = 0; r < 4; ++r) {
          int gm = m0 + wv * 32 + i * 16 + g * 4 + r;
          int b = gm >> 11, s = gm & 2047;
          O[(((size_t)b * 16 + h) * 2048 + s) * 64 + d] =
              f2bf_fast((acc[i][j][r] + bvv) * sc);
        }
    }
  }
}

// Old 128x128 epilogue kept for the cvt fallback path.
__device__ __forceinline__ void qkv_epilogue(
    floatx4 acc[4][4], const void* Bi, int cF32, u16* O, int m0, int n0,
    int tid, int z)
{
  const int lane = tid & 63, wv = tid >> 6;
  const int wm = wv >> 1, wn = wv & 1, g = lane >> 4, ml = lane & 15;
  const float sc = (z == 0) ? QSCALE : 1.0f;
#pragma unroll
  for (int j = 0; j < 4; ++j) {
    int gn = n0 + wn * 64 + j * 16 + ml;
    float bvv = ldscalar(Bi, (size_t)gn, cF32);
    int h = gn >> 6, d = gn & 63;
    if (z == 2) {
#pragma unroll
      for (int i = 0; i < 4; ++i) {
        int gm0 = m0 + wm * 64 + i * 16 + g * 4;
        int b = gm0 >> 11, s0 = gm0 & 2047;
        short4v pk;
#pragma unroll
        for (int r = 0; r < 4; ++r) pk[r] = (short)f2bf_fast(acc[i][j][r] + bvv);
        *(short4v*)(O + ((((size_t)b * 16 + h) * 64 + d) * 2048 + s0)) = pk;
      }
    } else {
#pragma unroll
      for (int i = 0; i < 4; ++i)
#pragma unroll
        for (int r = 0; r < 4; ++r) {
          int gm = m0 + wm * 64 + i * 16 + g * 4 + r;
          int b = gm >> 11, s = gm & 2047;
          O[(((size_t)b * 16 + h) * 2048 + s) * 64 + d] =
              f2bf_fast((acc[i][j][r] + bvv) * sc);
        }
    }
  }
}

// grid (32 m-tiles, 16 n-tiles, 3) = 1536 blocks -> 6 blocks/CU.
__global__ __launch_bounds__(256, 6) void qkv_gemm_bf16(
    const u16* __restrict__ Xq, const u16* __restrict__ Xk, const u16* __restrict__ Xv,
    const u16* __restrict__ Wq, const u16* __restrict__ Wk, const u16* __restrict__ Wv,
    const void* __restrict__ Bq, const void* __restrict__ Bk, const void* __restrict__ Bv,
    u16* __restrict__ Oq, u16* __restrict__ Ok, u16* __restrict__ Ov)
{
  __align__(16) __shared__ u16 As[8192];
  __align__(16) __shared__ u16 Bs[4096];
  const int z = blockIdx.z;
  const u16* X = (z == 0) ? Xq : (z == 1) ? Xk : Xv;
  const u16* W = (z == 0) ? Wq : (z == 1) ? Wk : Wv;
  const void* Bi = (z == 0) ? Bq : (z == 1) ? Bk : Bv;
  u16* O = (z == 0) ? Oq : (z == 1) ? Ok : Ov;
  const int tid = threadIdx.x;
  const int m0 = blockIdx.x * 128, n0 = blockIdx.y * 64;
  floatx4 acc[2][4] = {};
  gemm_core_bf16_n64(X, W, As, Bs, acc, m0, n0, 1024, tid);
  const int cF32 = probe_is_f32(Bi);   // after core: no stray vmem in loop
  qkv_epilogue64(acc, Bi, cF32, O, m0, n0, tid, z);
}

__global__ __launch_bounds__(256) void qkv_gemm_cvt(
    const void* __restrict__ Xq, const void* __restrict__ Xk, const void* __restrict__ Xv,
    const void* __restrict__ Wq, const void* __restrict__ Wk, const void* __restrict__ Wv,
    const void* __restrict__ Bq, const void* __restrict__ Bk, const void* __restrict__ Bv,
    u16* __restrict__ Oq, u16* __restrict__ Ok, u16* __restrict__ Ov)
{
  __align__(16) __shared__ u16 As[4096];
  __align__(16) __shared__ u16 Bs[4096];
  const int z = blockIdx.z;
  const void* X  = (z == 0) ? Xq : (z == 1) ? Xk : Xv;
  const void* W  = (z == 0) ? Wq : (z == 1) ? Wk : Wv;
  const void* Bi = (z == 0) ? Bq : (z == 1) ? Bk : Bv;
  u16* O = (z == 0) ? Oq : (z == 1) ? Ok : Ov;
  const int aF32 = probe_is_f32(X);
  const int bF32 = probe_is_f32(W);
  const int cF32 = probe_is_f32(Bi);
  const int tid = threadIdx.x;
  const int m0 = blockIdx.y * 128, n0 = blockIdx.x * 128;
  floatx4 acc[4][4] = {};
  gemm_core_cvt(X, W, aF32, bF32, As, Bs, acc, m0, n0, 1024, tid);
  qkv_epilogue(acc, Bi, cF32, O, m0, n0, tid, z);
}

// ---------------------------------------------------------------------------
// Output projection: 128x64 tiles, grid (32, 16) = 512 blocks. fp32 store.
// ---------------------------------------------------------------------------
__global__ __launch_bounds__(256, 6) void out_gemm_bf16(
    const u16* __restrict__ X, const u16* __restrict__ W,
    const void* __restrict__ Bi, float* __restrict__ O)
{
  __align__(16) __shared__ u16 As[8192];
  __align__(16) __shared__ u16 Bs[4096];
  const int tid = threadIdx.x;
  const int m0 = blockIdx.x * 128, n0 = blockIdx.y * 64;
  floatx4 acc[2][4] = {};
  gemm_core_bf16_n64(X, W, As, Bs, acc, m0, n0, 1024, tid);
  const int cF32 = probe_is_f32(Bi);
  const int lane = tid & 63, wv = tid >> 6;
  const int g = lane >> 4, ml = lane & 15;
#pragma unroll
  for (int j = 0; j < 4; ++j) {
    int gn = n0 + j * 16 + ml;
    float bvv = ldscalar(Bi, (size_t)gn, cF32);
#pragma unroll
    for (int i = 0; i < 2; ++i)
#pragma unroll
      for (int r = 0; r < 4; ++r) {
        int gm = m0 + wv * 32 + i * 16 + g * 4 + r;
        O[(size_t)gm * 1024 + gn] = acc[i][j][r] + bvv;
      }
  }
}

__global__ __launch_bounds__(256) void out_gemm_cvt(
    const u16* __restrict__ X, const void* __restrict__ W,
    const void* __restrict__ Bi, float* __restrict__ O)
{
  __align__(16) __shared__ u16 As[4096];
  __align__(16) __shared__ u16 Bs[4096];
  const int bF32 = probe_is_f32(W);
  const int cF32 = probe_is_f32(Bi);
  const int tid = threadIdx.x;
  const int m0 = blockIdx.y * 128, n0 = blockIdx.x * 128;
  floatx4 acc[4][4] = {};
  gemm_core_cvt(X, W, /*aF32=*/0, bF32, As, Bs, acc, m0, n0, 1024, tid);
  const int lane = tid & 63, wv = tid >> 6;
  const int wm = wv >> 1, wn = wv & 1, g = lane >> 4, ml = lane & 15;
#pragma unroll
  for (int j = 0; j < 4; ++j) {
    int gn = n0 + wn * 64 + j * 16 + ml;
    float bvv = ldscalar(Bi, (size_t)gn, cF32);
#pragma unroll
    for (int i = 0; i < 4; ++i)
#pragma unroll
      for (int r = 0; r < 4; ++r) {
        int gm = m0 + wm * 64 + i * 16 + g * 4 + r;
        O[(size_t)gm * 1024 + gn] = acc[i][j][r] + bvv;
      }
  }
}

// ---------------------------------------------------------------------------
// Flash attention v12: v11b + XCD-aware blockIdx swizzle (T1).
// R9 counters: FETCH 71.8 MB vs 25.2 ideal (2.85x). Default linear id =
// qt + 32*bh with id%8 -> XCD sprays same-(b,h) blocks across all 8 XCDs;
// every XCD fetches K/V for ~all 64 bh. Swizzle swz = (id&7)*128 + id>>3
// (bijective: 1024 = 8*128) makes XCD c host bh in [4c, 4c+4): K+V+Q
// footprint 4*(256+256+256)KB ~= 3 MB < 4 MB L2 -> K/V reads L2-hit after
// first touch. For a latency-bound kernel this converts ~900cyc HBM/L3
// misses into ~200cyc L2 hits. Kernel math unchanged from passing v11b.
// ---------------------------------------------------------------------------
__global__ __launch_bounds__(256, 4) void flash_attn(
    const u16* __restrict__ Q, const u16* __restrict__ K, const u16* __restrict__ V,
    const int* __restrict__ Mask, u16* __restrict__ O)
{
  __align__(16) __shared__ u16 Ks[2][64 * 64];   // doubles as f32 exchange buf
  __align__(16) __shared__ u16 Vt[2][64 * 64];
  __align__(16) __shared__ int Ms[64];
  __align__(16) __shared__ float Lf[256];
  __shared__ int Wok[4];

  // T1 swizzle: consecutive hardware ids (round-robin over XCDs) map so each
  // XCD owns a contiguous bh-range; qt varies fastest within an XCD.
  const int wgid = blockIdx.x + (blockIdx.y << 5);        // 0..1023
  const int swz  = ((wgid & 7) << 7) | (wgid >> 3);       // xcd*128 + idx
  const int qt = swz & 31;
  const int bh = swz >> 5;
  const int b = bh >> 4, h = bh & 15;
  const int tid = threadIdx.x;
  const int lane = tid & 63, wv = tid >> 6;
  const int qh = wv & 1, kh = wv >> 1;
  const int H = lane >> 5, lq = lane & 31;
  const int koff = lq * 16 + H * 8;        // lane slot offset within a subtile

  const size_t baseQ  = (((size_t)b * 16 + h) * 2048 + (size_t)qt * 64) * 64;
  const size_t baseKV = ((size_t)b * 16 + h) * 2048 * 64;  // V is [B,H,D,S]

  {
    int la = 1;
#pragma unroll
    for (int i = 0; i < 8; ++i) la &= Mask[b * 2048 + tid * 8 + i];
    int wall = __all(la != 0);
    if (lane == 0) Wok[wv] = wall;
  }

  // Q fragments (B-operand): rows q = qt*64 + qh*32 + lq, d = 16c + 8H + j
  short8 qf[4];
  {
    const u16* qb = Q + baseQ + (size_t)(qh * 32 + lq) * 64 + H * 8;
#pragma unroll
    for (int c = 0; c < 4; ++c)
      qf[c] = *(const short8*)(qb + c * 16);
  }

  // staging: 512 16B-slots over 256 threads x 2; subtile encoding in the
  // global source address, linear LDS dest (m173 pattern).
  const u16* kg[2]; const u16* vg[2];
  int lo[2];
#pragma unroll
  for (int t = 0; t < 2; ++t) {
    int s = tid + t * 256;
    int blk = s >> 8;                       // 32-row block
    int ch  = (s >> 6) & 3;                 // 16-u16 chunk
    int row = (s >> 1) & 31;
    int hh  = s & 1;
    kg[t] = K + baseKV + (size_t)(blk * 32 + row) * 64 + ch * 16 + hh * 8;
    vg[t] = V + baseKV + (size_t)(blk * 32 + row) * 2048 + ch * 16 + hh * 8;
    lo[t] = ((tid & 192) + t * 256) * 8;    // wave-uniform base (u16 units)
  }

  // prologue: K(0) -> Ks[0], V(0) -> Vt[0]
#pragma unroll
  for (int t = 0; t < 2; ++t) {
    __builtin_amdgcn_global_load_lds((const AS_GLOBAL unsigned int*)kg[t],
                                     (AS_LDS unsigned int*)(&Ks[0][0] + lo[t]), 16, 0, 0);
    __builtin_amdgcn_global_load_lds((const AS_GLOBAL unsigned int*)vg[t],
                                     (AS_LDS unsigned int*)(&Vt[0][0] + lo[t]), 16, 0, 0);
  }

  __syncthreads();
  const bool maskall = Wok[0] && Wok[1] && Wok[2] && Wok[3];

  floatx16 oacc0 = {}, oacc1 = {};
  float lp = 0.f;

  int buf = 0;
#pragma unroll 2
  for (int kv0 = 0; kv0 < 2048; kv0 += 64) {
    // prefetch NEXT tile (K and V) into buf^1 (dummy wrap on last iter).
    // K rows stride 64 (S-major); V kv index is stride-1 (S fastest).
    const int nxt = (kv0 + 64) & 2047;
#pragma unroll
    for (int t = 0; t < 2; ++t) {
      __builtin_amdgcn_global_load_lds((const AS_GLOBAL unsigned int*)(vg[t] + nxt),
                                       (AS_LDS unsigned int*)(&Vt[buf ^ 1][0] + lo[t]), 16, 0, 0);
      __builtin_amdgcn_global_load_lds((const AS_GLOBAL unsigned int*)(kg[t] + (size_t)nxt * 64),
                                       (AS_LDS unsigned int*)(&Ks[buf ^ 1][0] + lo[t]), 16, 0, 0);
    }
    if (!maskall && tid < 64) Ms[tid] = Mask[b * 2048 + kv0 + tid];
    // wait current tile (4 oldest: K(i),V(i) issued last iter); keep 4 new
    // prefetch ops in flight. lgkmcnt(0) covers the Ms ds_write (cold path).
    __asm__ __volatile__("s_waitcnt vmcnt(4) lgkmcnt(0)\n\ts_barrier" ::: "memory");

    const u16* Kc = &Ks[buf][0];
    floatx16 a = {};
    __builtin_amdgcn_s_setprio(1);
#pragma unroll
    for (int c = 0; c < 4; ++c) {
      short8 kb = *(const short8*)(Kc + (kh * 4 + c) * 512 + koff);
      a = __builtin_amdgcn_mfma_f32_32x32x16_bf16(kb, qf[c], a, 0, 0, 0);
    }
    __builtin_amdgcn_s_setprio(0);

    float sv[16];
#pragma unroll
    for (int r = 0; r < 16; ++r) sv[r] = a[r];
    if (!maskall) {
#pragma unroll
      for (int r = 0; r < 16; ++r) {
        int ko = 32 * kh + (r & 3) + 8 * (r >> 2) + 4 * H;
        if (Ms[ko] == 0) sv[r] = -1.0e30f;
      }
    }
#pragma unroll
    for (int r = 0; r < 16; ++r) {
      float p = __builtin_amdgcn_exp2f(sv[r]);
      sv[r] = p;
      lp += p;
    }

    // ---- in-register P transpose (T12 @ 32x32, one kv-block) ----
    unsigned int Wd[8];
#pragma unroll
    for (int i = 0; i < 8; ++i)
      Wd[i] = cvtpk_bf16(sv[2 * i], sv[2 * i + 1]);
    short8 pa[2];
#define MAKE_PA(dst_, Wsrc_, base_) do {                                       \
    unsigned int u0 = Wsrc_[base_],       u1 = Wsrc_[(base_) + 1];             \
    unsigned int v0 = Wsrc_[(base_) + 2], v1 = Wsrc_[(base_) + 3];             \
    pl32_swap(u0, v0); pl32_swap(u1, v1);                                      \
    uint4v pw; pw[0] = u0; pw[1] = u1; pw[2] = v0; pw[3] = v1;                 \
    dst_ = __builtin_bit_cast(short8, pw);                                     \
  } while (0)
    MAKE_PA(pa[0], Wd, 0);
    MAKE_PA(pa[1], Wd, 4);
#undef MAKE_PA

    // PV directly: V(i) landed (covered by the vmcnt(4) above).
    const u16* Vc = &Vt[buf][0];
    __builtin_amdgcn_s_setprio(1);
#pragma unroll
    for (int c = 0; c < 2; ++c) {
      short8 vb = *(const short8*)(Vc + (2 * kh + c) * 512 + koff);           // db=0
      oacc0 = __builtin_amdgcn_mfma_f32_32x32x16_bf16(pa[c], vb, oacc0, 0, 0, 0);
    }
#pragma unroll
    for (int c = 0; c < 2; ++c) {
      short8 vb = *(const short8*)(Vc + (4 + 2 * kh + c) * 512 + koff);      // db=1
      oacc1 = __builtin_amdgcn_mfma_f32_32x32x16_bf16(pa[c], vb, oacc1, 0, 0, 0);
    }
    __builtin_amdgcn_s_setprio(0);

    // all waves done reading Ks[buf] + Vt[buf] -> next iter may prefetch
    // into buf (which becomes its buf^1)
    __asm__ __volatile__("s_barrier" ::: "memory");
    buf ^= 1;
  }
  // drain dummy prefetch; barrier before reusing Ks as the exchange buffer
  __asm__ __volatile__("s_waitcnt vmcnt(0)" ::: "memory");
  __syncthreads();

  // ---- cross-wave (kh) combine ----
  // l: in-wave H-combine, then exchange with partner wave (wv ^ 2)
  float lh = lp + __shfl_xor(lp, 32);
  Lf[wv * 64 + lane] = lh;
  // O partials: deposit the d-half this wave will NOT store.
  // Region per wave: 1024 floats at Xf + wv*1024; chunk layout w*256 + lane*4
  // (lane-contiguous float4s -> conflict-free).
  float* Xf = (float*)&Ks[0][0];
  {
    float* myreg = Xf + wv * 1024;
    const floatx16& dep = kh ? oacc0 : oacc1;   // kh0 deposits d-high, kh1 d-low
#pragma unroll
    for (int w = 0; w < 4; ++w) {
      float4 f4;
      f4.x = dep[4 * w + 0]; f4.y = dep[4 * w + 1];
      f4.z = dep[4 * w + 2]; f4.w = dep[4 * w + 3];
      *(float4*)(myreg + w * 256 + lane * 4) = f4;
    }
  }
  __syncthreads();
  const int pwv = wv ^ 2;
  float l = lh + Lf[pwv * 64 + lane];
  float inv = (l > 0.f) ? 1.0f / l : 0.f;
  floatx16 mine = kh ? oacc1 : oacc0;           // the d-half this wave stores
  {
    const float* prr = Xf + pwv * 1024;
#pragma unroll
    for (int w = 0; w < 4; ++w) {
      float4 f4 = *(const float4*)(prr + w * 256 + lane * 4);
      mine[4 * w + 0] += f4.x; mine[4 * w + 1] += f4.y;
      mine[4 * w + 2] += f4.z; mine[4 * w + 3] += f4.w;
    }
  }

#pragma unroll
  for (int r = 0; r < 16; ++r) {
    int qo = (r & 3) + 8 * (r >> 2) + 4 * H;
    float ivr = __shfl(inv, qo);           // inv lives at lane qo (q-col = qo)
    int q = qt * 64 + qh * 32 + qo;
    size_t orow = ((size_t)b * 2048 + q) * 1024 + (size_t)h * 64;
    O[orow + kh * 32 + lq] = f2bf_fast(mine[r] * ivr);
  }
}

// ---------------------------------------------------------------------------
extern "C" void kernel_launch(void* const* d_in, const int* in_sizes, int n_in,
                              void* d_out, int out_size, void* d_ws, size_t ws_size,
                              hipStream_t stream) {
  const void* q_in = d_in[0];
  const void* k_in = d_in[1];
  const void* v_in = d_in[2];
  const int* mask = (const int*)d_in[3];
  const void* Wq = d_in[4];  const void* bq = d_in[5];
  const void* Wk = d_in[6];  const void* bk = d_in[7];
  const void* Wv = d_in[8];  const void* bv = d_in[9];
  const void* Wo = d_in[10]; const void* bo = d_in[11];

  const size_t NTOK = (size_t)2 * 2048 * 1024;   // 4,194,304
  const size_t NW   = (size_t)1024 * 1024;       // 1,048,576

  if (ws_size >= (size_t)67108864) {
    u16* CXq = (u16*)d_ws;
    u16* CXk = CXq + NTOK;
    u16* CXv = CXk + NTOK;
    u16* CWq = CXv + NTOK;
    u16* CWk = CWq + NW;
    u16* CWv = CWk + NW;
    u16* CWo = CWv + NW;
    u16* Qp  = CWo + NW;
    u16* Kp  = Qp + NTOK;
    u16* Vp  = Kp + NTOK;   // [B,H,D,S]
    u16* Ao  = Vp + NTOK;

    cvt7<<<dim3(1024, 7), 256, 0, stream>>>(q_in, k_in, v_in, Wq, Wk, Wv, Wo,
                                            CXq, CXk, CXv, CWq, CWk, CWv, CWo);
    qkv_gemm_bf16<<<dim3(32, 16, 3), 256, 0, stream>>>(CXq, CXk, CXv,
                                                       CWq, CWk, CWv,
                                                       bq, bk, bv, Qp, Kp, Vp);
    flash_attn<<<dim3(32, 32), 256, 0, stream>>>(Qp, Kp, Vp, mask, Ao);
    out_gemm_bf16<<<dim3(32, 16), 256, 0, stream>>>(Ao, CWo, bo, (float*)d_out);
  } else {
    u16* Qp = (u16*)d_ws;
    u16* Kp = Qp + NTOK;
    u16* Vp = Kp + NTOK;    // [B,H,D,S]
    u16* Ao  = Vp + NTOK;

    qkv_gemm_cvt<<<dim3(8, 32, 3), 256, 0, stream>>>(q_in, k_in, v_in,
                                                     Wq, Wk, Wv, bq, bk, bv,
                                                     Qp, Kp, Vp);
    flash_attn<<<dim3(32, 32), 256, 0, stream>>>(Qp, Kp, Vp, mask, Ao);
    out_gemm_cvt<<<dim3(8, 32), 256, 0, stream>>>(Ao, Wo, bo, (float*)d_out);
  }
}